// Round 1
// baseline (1122.890 us; speedup 1.0000x reference)
//
#include <hip/hip_runtime.h>

constexpr int Bn  = 16;
constexpr int Tn  = 512;
constexpr int Dn  = 512;
constexpr int Hn  = 16;
constexpr int DHn = 32;
constexpr int Pn  = 1023;   // 2T-1

// ---------------------------------------------------------------------------
// Mask decode: detect layout (int32 / byte-bool / float32) then write 0/1 flags
// ---------------------------------------------------------------------------
__global__ void mask_decode_kernel(const unsigned char* __restrict__ mraw,
                                   float* __restrict__ mout) {
    __shared__ int s_nonmod4;  // any nonzero byte at offset%4!=0
    __shared__ int s_big;      // any byte value > 1  (float exponent bytes)
    if (threadIdx.x == 0) { s_nonmod4 = 0; s_big = 0; }
    __syncthreads();
    int f0 = 0, f1 = 0;
    for (int i = threadIdx.x; i < Bn * Tn; i += 256) {   // first 8192 bytes: safe in all layouts
        unsigned char v = mraw[i];
        if ((i & 3) != 0 && v != 0) f0 = 1;
        if (v > 1) f1 = 1;
    }
    if (f0) atomicOr(&s_nonmod4, 1);
    if (f1) atomicOr(&s_big, 1);
    __syncthreads();
    const int layout = s_big ? 2 : (s_nonmod4 ? 1 : 0); // 2=float32 1=byte 0=int32
    for (int i = threadIdx.x; i < Bn * Tn; i += 256) {
        bool m;
        if (layout == 2)      m = ((const float*)mraw)[i] != 0.0f;
        else if (layout == 1) m = mraw[i] != 0;
        else                  m = ((const int*)mraw)[i] != 0;
        mout[i] = m ? 1.0f : 0.0f;
    }
}

// ---------------------------------------------------------------------------
// Fused conv bias: bpp_bias = conv2(relu(conv1(bpp))), 3x3 SAME, 1->16->1 ch.
// One block per 32x32 output tile; per-channel LDS double buffer.
// ---------------------------------------------------------------------------
__global__ __launch_bounds__(256) void conv_bias_kernel(
    const float* __restrict__ bpp, const float* __restrict__ c1w,
    const float* __restrict__ c1b, const float* __restrict__ c2w,
    const float* __restrict__ c2b, float* __restrict__ biasout) {
    const int x0 = blockIdx.x * 32, y0 = blockIdx.y * 32, b = blockIdx.z;
    __shared__ float inb[36][37];
    __shared__ float h1c[2][34][35];
    __shared__ float w1[16][9], w2[16][9], b1[16];
    const int tid = threadIdx.x;
    if (tid < 144) { w1[tid / 9][tid % 9] = c1w[tid]; w2[tid / 9][tid % 9] = c2w[tid]; }
    if (tid < 16) b1[tid] = c1b[tid];
    const float* src = bpp + (size_t)b * Tn * Tn;
    for (int i = tid; i < 36 * 36; i += 256) {
        int yy = i / 36, xx = i % 36;
        int ya = y0 - 2 + yy, xa = x0 - 2 + xx;
        float v = 0.0f;
        if (ya >= 0 && ya < Tn && xa >= 0 && xa < Tn) v = src[(size_t)ya * Tn + xa];
        inb[yy][xx] = v;
    }
    __syncthreads();
    float acc[4] = {0.f, 0.f, 0.f, 0.f};
    for (int ch = 0; ch < 16; ++ch) {
        const int buf = ch & 1;
        for (int i = tid; i < 34 * 34; i += 256) {
            int yy = i / 34, xx = i % 34;
            int ya = y0 - 1 + yy, xa = x0 - 1 + xx;
            float v = 0.0f;
            if (ya >= 0 && ya < Tn && xa >= 0 && xa < Tn) {
                float s = b1[ch];
#pragma unroll
                for (int dy = 0; dy < 3; ++dy)
#pragma unroll
                    for (int dx = 0; dx < 3; ++dx)
                        s += inb[yy + dy][xx + dx] * w1[ch][dy * 3 + dx];
                v = fmaxf(s, 0.0f);
            }
            h1c[buf][yy][xx] = v;
        }
        __syncthreads();
#pragma unroll
        for (int r = 0; r < 4; ++r) {
            int o = tid + 256 * r;
            int oy = o >> 5, ox = o & 31;
            float s = 0.0f;
#pragma unroll
            for (int dy = 0; dy < 3; ++dy)
#pragma unroll
                for (int dx = 0; dx < 3; ++dx)
                    s += h1c[buf][oy + dy][ox + dx] * w2[ch][dy * 3 + dx];
            acc[r] += s;
        }
        // next iteration writes the other buffer; the sync above orders reuse
    }
    const float ob = c2b[0];
#pragma unroll
    for (int r = 0; r < 4; ++r) {
        int o = tid + 256 * r;
        int oy = o >> 5, ox = o & 31;
        biasout[((size_t)b * Tn + y0 + oy) * Tn + (x0 + ox)] = acc[r] + ob;
    }
}

// ---------------------------------------------------------------------------
// f32 GEMM: out = A @ W^T (+bias). A:[M,512] W:[512,512] row-major (n,k).
// 64x64 tile, BK=32, k-major LDS, 4x4 per thread.
// scatter=1: out[((b*H+h)*L+t)*32+d] with m=b*L+t, n=h*32+d ; scatter=0: [M,512]
// ---------------------------------------------------------------------------
__global__ __launch_bounds__(256) void gemm_f32_kernel(
    const float* __restrict__ A, const float* __restrict__ W,
    const float* __restrict__ bias, float* __restrict__ out,
    int M, int L, int scatter) {
    constexpr int K = 512;
    __shared__ __align__(16) float As[32][68];
    __shared__ __align__(16) float Bs[32][68];
    const int tid = threadIdx.x;
    const int nbase = blockIdx.x * 64;
    const int mbase = blockIdx.y * 64;
    const int mloc = (tid & 15) * 4, nloc = (tid >> 4) * 4;
    float acc[4][4] = {};
    for (int k0 = 0; k0 < K; k0 += 32) {
#pragma unroll
        for (int r = 0; r < 2; ++r) {
            int f = tid + 256 * r;
            int row = f >> 3, kq = f & 7;
            int m = mbase + row;
            float4 v = make_float4(0.f, 0.f, 0.f, 0.f);
            if (m < M) v = *(const float4*)(A + (size_t)m * K + k0 + kq * 4);
            As[kq * 4 + 0][row] = v.x; As[kq * 4 + 1][row] = v.y;
            As[kq * 4 + 2][row] = v.z; As[kq * 4 + 3][row] = v.w;
        }
#pragma unroll
        for (int r = 0; r < 2; ++r) {
            int f = tid + 256 * r;
            int row = f >> 3, kq = f & 7;
            float4 v = *(const float4*)(W + (size_t)(nbase + row) * K + k0 + kq * 4);
            Bs[kq * 4 + 0][row] = v.x; Bs[kq * 4 + 1][row] = v.y;
            Bs[kq * 4 + 2][row] = v.z; Bs[kq * 4 + 3][row] = v.w;
        }
        __syncthreads();
#pragma unroll
        for (int k = 0; k < 32; ++k) {
            float4 a4 = *(const float4*)&As[k][mloc];
            float4 b4 = *(const float4*)&Bs[k][nloc];
            float av[4] = {a4.x, a4.y, a4.z, a4.w};
            float bv[4] = {b4.x, b4.y, b4.z, b4.w};
#pragma unroll
            for (int i = 0; i < 4; ++i)
#pragma unroll
                for (int j = 0; j < 4; ++j)
                    acc[i][j] += av[i] * bv[j];
        }
        __syncthreads();
    }
#pragma unroll
    for (int j = 0; j < 4; ++j) {
        const int n = nbase + nloc + j;
        const float bv = bias ? bias[n] : 0.0f;
#pragma unroll
        for (int i = 0; i < 4; ++i) {
            const int m = mbase + mloc + i;
            if (m < M) {
                size_t oidx;
                if (scatter) {
                    int bb = m / L, t = m - bb * L;
                    int hh = n >> 5, d = n & 31;
                    oidx = (((size_t)bb * Hn + hh) * L + t) * DHn + d;
                } else {
                    oidx = (size_t)m * 512 + n;
                }
                out[oidx] = acc[i][j] + bv;
            }
        }
    }
}

// ---------------------------------------------------------------------------
// Fused attention: per (b, h, 16-row t-block).
// scores (content + shifted pos)/sqrt(dh) + conv-bias, mask, softmax, PV.
// relative shift: shifted[t,s] = pos_score[t, s - t + (T-1)]
// ---------------------------------------------------------------------------
__global__ __launch_bounds__(256) void attn_kernel(
    const float* __restrict__ qw, const float* __restrict__ kw,
    const float* __restrict__ vw, const float* __restrict__ pw,
    const float* __restrict__ biasw, const float* __restrict__ maskw,
    const float* __restrict__ ub, const float* __restrict__ vb,
    float* __restrict__ ctx) {
    const int t0 = blockIdx.x * 16, h = blockIdx.y, b = blockIdx.z;
    __shared__ __align__(16) float kc[64][36];
    __shared__ __align__(16) float pc[80][36];
    __shared__ float at[16][516];
    __shared__ __align__(16) float pvp[2][16][32];
    const int tid = threadIdx.x;
    const size_t bh = (size_t)b * Hn + h;
    const float* qbase = qw + bh * Tn * DHn;
    const float* kbase = kw + bh * Tn * DHn;
    const float* vbase = vw + bh * Tn * DHn;
    const float* pbase = pw + bh * Pn * DHn;

    const int t = tid >> 4, sc = tid & 15;
    // q row (+u / +v bias) into registers; 16 lanes per t broadcast from L1.
    float quR[32], qvR[32];
#pragma unroll
    for (int dq = 0; dq < 8; ++dq) {
        float4 qf = *(const float4*)(qbase + (size_t)(t0 + t) * DHn + dq * 4);
        float4 uf = *(const float4*)(ub + h * DHn + dq * 4);
        float4 vf = *(const float4*)(vb + h * DHn + dq * 4);
        quR[dq * 4 + 0] = qf.x + uf.x; quR[dq * 4 + 1] = qf.y + uf.y;
        quR[dq * 4 + 2] = qf.z + uf.z; quR[dq * 4 + 3] = qf.w + uf.w;
        qvR[dq * 4 + 0] = qf.x + vf.x; qvR[dq * 4 + 1] = qf.y + vf.y;
        qvR[dq * 4 + 2] = qf.z + vf.z; qvR[dq * 4 + 3] = qf.w + vf.w;
    }
    float r[32];
    float mx = -1e30f;
    const float scale = 0.17677669529663687f;  // 1/sqrt(32)
#pragma unroll
    for (int chunk = 0; chunk < 8; ++chunk) {
        __syncthreads();  // previous chunk's reads done before overwrite
#pragma unroll
        for (int rr = 0; rr < 2; ++rr) {
            int f = tid + 256 * rr;
            int row = f >> 3, kq = f & 7;
            float4 v = *(const float4*)(kbase + (size_t)(chunk * 64 + row) * DHn + kq * 4);
            *(float4*)&kc[row][kq * 4] = v;
        }
        const int relmin = chunk * 64 + (Tn - 1) - t0 - 15;
        for (int f = tid; f < 80 * 8; f += 256) {
            int row = f >> 3, kq = f & 7;
            int pr = relmin + row; if (pr > Pn - 1) pr = Pn - 1;  // clamp (unused rows)
            float4 v = *(const float4*)(pbase + (size_t)pr * DHn + kq * 4);
            *(float4*)&pc[row][kq * 4] = v;
        }
        __syncthreads();
#pragma unroll
        for (int so = 0; so < 4; ++so) {
            const int s_loc = sc + 16 * so;
            const int s = chunk * 64 + s_loc;
            const int pidx = s_loc + 15 - t;   // (s + T-1 - t_abs) - relmin
            float csum = 0.f, psum = 0.f;
#pragma unroll
            for (int dq = 0; dq < 8; ++dq) {
                float4 kf = *(const float4*)&kc[s_loc][dq * 4];
                float4 pf = *(const float4*)&pc[pidx][dq * 4];
                csum += quR[dq * 4 + 0] * kf.x + quR[dq * 4 + 1] * kf.y
                      + quR[dq * 4 + 2] * kf.z + quR[dq * 4 + 3] * kf.w;
                psum += qvR[dq * 4 + 0] * pf.x + qvR[dq * 4 + 1] * pf.y
                      + qvR[dq * 4 + 2] * pf.z + qvR[dq * 4 + 3] * pf.w;
            }
            float raw = (csum + psum) * scale
                        + biasw[((size_t)b * Tn + t0 + t) * Tn + s];
            if (maskw[b * Tn + s] != 0.0f) raw = -10000.0f;
            r[chunk * 4 + so] = raw;
            mx = fmaxf(mx, raw);
        }
    }
#pragma unroll
    for (int off = 1; off < 16; off <<= 1) mx = fmaxf(mx, __shfl_xor(mx, off, 64));
    float sum = 0.f;
#pragma unroll
    for (int i = 0; i < 32; ++i) { float e = __expf(r[i] - mx); r[i] = e; sum += e; }
#pragma unroll
    for (int off = 1; off < 16; off <<= 1) sum += __shfl_xor(sum, off, 64);
    const float inv = 1.0f / sum;
#pragma unroll
    for (int chunk = 0; chunk < 8; ++chunk)
#pragma unroll
        for (int so = 0; so < 4; ++so)
            at[t][chunk * 64 + 16 * so + sc] = r[chunk * 4 + so] * inv;
    __syncthreads();
    // PV: 2 s-halves x 16 t x 8 dquads
    {
        const int sq = tid >> 7, rest = tid & 127;
        const int tt = rest >> 3, dq = rest & 7;
        float4 acc = make_float4(0.f, 0.f, 0.f, 0.f);
        for (int sl = 0; sl < 256; ++sl) {
            int s = sq * 256 + sl;
            float a = at[tt][s];
            float4 v = *(const float4*)(vbase + (size_t)s * DHn + dq * 4);
            acc.x += a * v.x; acc.y += a * v.y; acc.z += a * v.z; acc.w += a * v.w;
        }
        *(float4*)&pvp[sq][tt][dq * 4] = acc;
    }
    __syncthreads();
    if (tid < 128) {
        const int tt = tid >> 3, dq = tid & 7;
        float4 a = *(const float4*)&pvp[0][tt][dq * 4];
        float4 c = *(const float4*)&pvp[1][tt][dq * 4];
        float4 o = make_float4(a.x + c.x, a.y + c.y, a.z + c.z, a.w + c.w);
        *(float4*)(ctx + (((size_t)b * Tn + t0 + tt) * Hn + h) * DHn + dq * 4) = o;
    }
}

// ---------------------------------------------------------------------------
extern "C" void kernel_launch(void* const* d_in, const int* in_sizes, int n_in,
                              void* d_out, int out_size, void* d_ws, size_t ws_size,
                              hipStream_t stream) {
    const float* query = (const float*)d_in[0];
    const float* key   = (const float*)d_in[1];
    const float* value = (const float*)d_in[2];
    const float* pos   = (const float*)d_in[3];
    const unsigned char* mask = (const unsigned char*)d_in[4];
    const float* bpp = (const float*)d_in[5];
    const float* Wq = (const float*)d_in[6];
    const float* bq = (const float*)d_in[7];
    const float* Wk = (const float*)d_in[8];
    const float* bk = (const float*)d_in[9];
    const float* Wv = (const float*)d_in[10];
    const float* bv = (const float*)d_in[11];
    const float* Wp = (const float*)d_in[12];
    const float* Wo = (const float*)d_in[13];
    const float* bo = (const float*)d_in[14];
    const float* ub = (const float*)d_in[15];
    const float* vbias = (const float*)d_in[16];
    const float* c1w = (const float*)d_in[17];
    const float* c1b = (const float*)d_in[18];
    const float* c2w = (const float*)d_in[19];
    const float* c2b = (const float*)d_in[20];

    float* ws = (float*)d_ws;
    float* q_ws    = ws;                                   // [B,H,T,DH]
    float* k_ws    = q_ws  + (size_t)Bn * Hn * Tn * DHn;   // [B,H,T,DH]
    float* v_ws    = k_ws  + (size_t)Bn * Hn * Tn * DHn;   // [B,H,T,DH]
    float* p_ws    = v_ws  + (size_t)Bn * Hn * Tn * DHn;   // [B,H,P,DH]
    float* bias_ws = p_ws  + (size_t)Bn * Hn * Pn * DHn;   // [B,T,T]
    float* ctx_ws  = bias_ws + (size_t)Bn * Tn * Tn;       // [B,T,H,DH]
    float* mask_ws = ctx_ws + (size_t)Bn * Tn * Dn;        // [B,T]

    mask_decode_kernel<<<dim3(1), dim3(256), 0, stream>>>(mask, mask_ws);
    conv_bias_kernel<<<dim3(16, 16, Bn), dim3(256), 0, stream>>>(
        bpp, c1w, c1b, c2w, c2b, bias_ws);
    gemm_f32_kernel<<<dim3(8, 128), dim3(256), 0, stream>>>(
        query, Wq, bq, q_ws, Bn * Tn, Tn, 1);
    gemm_f32_kernel<<<dim3(8, 128), dim3(256), 0, stream>>>(
        key, Wk, bk, k_ws, Bn * Tn, Tn, 1);
    gemm_f32_kernel<<<dim3(8, 128), dim3(256), 0, stream>>>(
        value, Wv, bv, v_ws, Bn * Tn, Tn, 1);
    gemm_f32_kernel<<<dim3(8, 256), dim3(256), 0, stream>>>(
        pos, Wp, (const float*)nullptr, p_ws, Bn * Pn, Pn, 1);
    attn_kernel<<<dim3(Tn / 16, Hn, Bn), dim3(256), 0, stream>>>(
        q_ws, k_ws, v_ws, p_ws, bias_ws, mask_ws, ub, vbias, ctx_ws);
    gemm_f32_kernel<<<dim3(8, 128), dim3(256), 0, stream>>>(
        ctx_ws, Wo, bo, (float*)d_out, Bn * Tn, Tn, 0);
}

// Round 2
// 933.588 us; speedup vs baseline: 1.2028x; 1.2028x over previous
//
#include <hip/hip_runtime.h>

constexpr int Bn  = 16;
constexpr int Tn  = 512;
constexpr int Dn  = 512;
constexpr int Hn  = 16;
constexpr int DHn = 32;
constexpr int Pn  = 1023;   // 2T-1

typedef __attribute__((ext_vector_type(8))) short s16x8;
typedef __attribute__((ext_vector_type(4))) float f32x4;

__device__ inline unsigned short f2bf(float x) {
    unsigned u = __float_as_uint(x);
    unsigned r = u + 0x7fff + ((u >> 16) & 1);
    return (unsigned short)(r >> 16);
}
__device__ inline float bf2f(unsigned short h) {
    return __uint_as_float(((unsigned)h) << 16);
}

// ---------------------------------------------------------------------------
// Split f32 -> (hi, lo) bf16 planes. n4 = element_count / 4.
// ---------------------------------------------------------------------------
__global__ __launch_bounds__(256) void split_bf16_kernel(
    const float* __restrict__ in, unsigned short* __restrict__ hi,
    unsigned short* __restrict__ lo, int n4) {
    for (int i = blockIdx.x * 256 + threadIdx.x; i < n4; i += gridDim.x * 256) {
        float4 v = ((const float4*)in)[i];
        ushort4 h, l;
        h.x = f2bf(v.x); l.x = f2bf(v.x - bf2f(h.x));
        h.y = f2bf(v.y); l.y = f2bf(v.y - bf2f(h.y));
        h.z = f2bf(v.z); l.z = f2bf(v.z - bf2f(h.z));
        h.w = f2bf(v.w); l.w = f2bf(v.w - bf2f(h.w));
        ((ushort4*)hi)[i] = h;
        ((ushort4*)lo)[i] = l;
    }
}

// ---------------------------------------------------------------------------
// Mask decode: detect layout (int32 / byte-bool / float32) then write 0/1 flags
// ---------------------------------------------------------------------------
__global__ void mask_decode_kernel(const unsigned char* __restrict__ mraw,
                                   float* __restrict__ mout) {
    __shared__ int s_nonmod4;
    __shared__ int s_big;
    if (threadIdx.x == 0) { s_nonmod4 = 0; s_big = 0; }
    __syncthreads();
    int f0 = 0, f1 = 0;
    for (int i = threadIdx.x; i < Bn * Tn; i += 256) {
        unsigned char v = mraw[i];
        if ((i & 3) != 0 && v != 0) f0 = 1;
        if (v > 1) f1 = 1;
    }
    if (f0) atomicOr(&s_nonmod4, 1);
    if (f1) atomicOr(&s_big, 1);
    __syncthreads();
    const int layout = s_big ? 2 : (s_nonmod4 ? 1 : 0);
    for (int i = threadIdx.x; i < Bn * Tn; i += 256) {
        bool m;
        if (layout == 2)      m = ((const float*)mraw)[i] != 0.0f;
        else if (layout == 1) m = mraw[i] != 0;
        else                  m = ((const int*)mraw)[i] != 0;
        mout[i] = m ? 1.0f : 0.0f;
    }
}

// ---------------------------------------------------------------------------
// Fused conv bias: bpp_bias = conv2(relu(conv1(bpp))), 3x3 SAME, 1->16->1 ch.
// ---------------------------------------------------------------------------
__global__ __launch_bounds__(256) void conv_bias_kernel(
    const float* __restrict__ bpp, const float* __restrict__ c1w,
    const float* __restrict__ c1b, const float* __restrict__ c2w,
    const float* __restrict__ c2b, float* __restrict__ biasout) {
    const int x0 = blockIdx.x * 32, y0 = blockIdx.y * 32, b = blockIdx.z;
    __shared__ float inb[36][37];
    __shared__ float h1c[2][34][35];
    __shared__ float w1[16][9], w2[16][9], b1[16];
    const int tid = threadIdx.x;
    if (tid < 144) { w1[tid / 9][tid % 9] = c1w[tid]; w2[tid / 9][tid % 9] = c2w[tid]; }
    if (tid < 16) b1[tid] = c1b[tid];
    const float* src = bpp + (size_t)b * Tn * Tn;
    for (int i = tid; i < 36 * 36; i += 256) {
        int yy = i / 36, xx = i % 36;
        int ya = y0 - 2 + yy, xa = x0 - 2 + xx;
        float v = 0.0f;
        if (ya >= 0 && ya < Tn && xa >= 0 && xa < Tn) v = src[(size_t)ya * Tn + xa];
        inb[yy][xx] = v;
    }
    __syncthreads();
    float acc[4] = {0.f, 0.f, 0.f, 0.f};
    for (int ch = 0; ch < 16; ++ch) {
        const int buf = ch & 1;
        for (int i = tid; i < 34 * 34; i += 256) {
            int yy = i / 34, xx = i % 34;
            int ya = y0 - 1 + yy, xa = x0 - 1 + xx;
            float v = 0.0f;
            if (ya >= 0 && ya < Tn && xa >= 0 && xa < Tn) {
                float s = b1[ch];
#pragma unroll
                for (int dy = 0; dy < 3; ++dy)
#pragma unroll
                    for (int dx = 0; dx < 3; ++dx)
                        s += inb[yy + dy][xx + dx] * w1[ch][dy * 3 + dx];
                v = fmaxf(s, 0.0f);
            }
            h1c[buf][yy][xx] = v;
        }
        __syncthreads();
#pragma unroll
        for (int r = 0; r < 4; ++r) {
            int o = tid + 256 * r;
            int oy = o >> 5, ox = o & 31;
            float s = 0.0f;
#pragma unroll
            for (int dy = 0; dy < 3; ++dy)
#pragma unroll
                for (int dx = 0; dx < 3; ++dx)
                    s += h1c[buf][oy + dy][ox + dx] * w2[ch][dy * 3 + dx];
            acc[r] += s;
        }
    }
    const float ob = c2b[0];
#pragma unroll
    for (int r = 0; r < 4; ++r) {
        int o = tid + 256 * r;
        int oy = o >> 5, ox = o & 31;
        biasout[((size_t)b * Tn + y0 + oy) * Tn + (x0 + ox)] = acc[r] + ob;
    }
}

// ---------------------------------------------------------------------------
// Split-bf16 MFMA GEMM: out = A @ W^T (+bias), A:[M,512], W:[512,512] (n,k).
// A = Ah+Al, W = Wh+Wl (bf16 planes). 3 MFMAs per product (hh, hl, lh).
// 128x128 tile, BK=32, 4 waves x (64x64). LDS rows padded to 40 elems (80 B).
// scatter=1: out[((b*H+h)*L+t)*32+d]; scatter=0: out[m*512+n].
// ---------------------------------------------------------------------------
__global__ __launch_bounds__(256) void gemm_mfma_split_kernel(
    const unsigned short* __restrict__ Ah, const unsigned short* __restrict__ Al,
    const unsigned short* __restrict__ Wh, const unsigned short* __restrict__ Wl,
    const float* __restrict__ bias, float* __restrict__ out,
    int M, int L, int scatter) {
    constexpr int K = 512, BK = 32, LDT = 40;
    __shared__ __align__(16) unsigned short AhT[128 * LDT];
    __shared__ __align__(16) unsigned short AlT[128 * LDT];
    __shared__ __align__(16) unsigned short WhT[128 * LDT];
    __shared__ __align__(16) unsigned short WlT[128 * LDT];
    const int tid = threadIdx.x;
    const int nbase = blockIdx.x * 128, mbase = blockIdx.y * 128;
    const int wave = tid >> 6, lane = tid & 63;
    const int wr = wave >> 1, wc = wave & 1;
    const int lg = lane >> 4, lr = lane & 15;
    f32x4 acc[4][4] = {};
    for (int k0 = 0; k0 < K; k0 += BK) {
        __syncthreads();
#pragma unroll
        for (int c = 0; c < 2; ++c) {
            const int idx = tid + 256 * c;
            const int r = idx >> 2, cb = (idx & 3) * 8;
            int gm = mbase + r; if (gm >= M) gm = M - 1;
            const size_t ga = (size_t)gm * K + k0 + cb;
            const size_t gw = (size_t)(nbase + r) * K + k0 + cb;
            const int loff = r * LDT + cb;
            *(s16x8*)&AhT[loff] = *(const s16x8*)&Ah[ga];
            *(s16x8*)&AlT[loff] = *(const s16x8*)&Al[ga];
            *(s16x8*)&WhT[loff] = *(const s16x8*)&Wh[gw];
            *(s16x8*)&WlT[loff] = *(const s16x8*)&Wl[gw];
        }
        __syncthreads();
        s16x8 wh[4], wl[4];
#pragma unroll
        for (int nj = 0; nj < 4; ++nj) {
            const int off = (wc * 64 + nj * 16 + lr) * LDT + lg * 8;
            wh[nj] = *(const s16x8*)&WhT[off];
            wl[nj] = *(const s16x8*)&WlT[off];
        }
#pragma unroll
        for (int mi = 0; mi < 4; ++mi) {
            const int off = (wr * 64 + mi * 16 + lr) * LDT + lg * 8;
            s16x8 ah = *(const s16x8*)&AhT[off];
            s16x8 al = *(const s16x8*)&AlT[off];
#pragma unroll
            for (int nj = 0; nj < 4; ++nj)
                acc[mi][nj] = __builtin_amdgcn_mfma_f32_16x16x32_bf16(ah, wh[nj], acc[mi][nj], 0, 0, 0);
#pragma unroll
            for (int nj = 0; nj < 4; ++nj)
                acc[mi][nj] = __builtin_amdgcn_mfma_f32_16x16x32_bf16(ah, wl[nj], acc[mi][nj], 0, 0, 0);
#pragma unroll
            for (int nj = 0; nj < 4; ++nj)
                acc[mi][nj] = __builtin_amdgcn_mfma_f32_16x16x32_bf16(al, wh[nj], acc[mi][nj], 0, 0, 0);
        }
    }
#pragma unroll
    for (int nj = 0; nj < 4; ++nj) {
        const int n = nbase + wc * 64 + nj * 16 + lr;
        const float bv = bias ? bias[n] : 0.0f;
#pragma unroll
        for (int mi = 0; mi < 4; ++mi) {
#pragma unroll
            for (int r2 = 0; r2 < 4; ++r2) {
                const int m = mbase + wr * 64 + mi * 16 + lg * 4 + r2;
                if (m < M) {
                    size_t oidx;
                    if (scatter) {
                        int bb = m / L, t = m - bb * L;
                        int hh = n >> 5, d = n & 31;
                        oidx = (((size_t)bb * Hn + hh) * L + t) * DHn + d;
                    } else {
                        oidx = (size_t)m * 512 + n;
                    }
                    out[oidx] = acc[mi][nj][r2] + bv;
                }
            }
        }
    }
}

// ---------------------------------------------------------------------------
// Fallback f32 GEMM (used if ws_size is too small for bf16 planes).
// ---------------------------------------------------------------------------
__global__ __launch_bounds__(256) void gemm_f32_kernel(
    const float* __restrict__ A, const float* __restrict__ W,
    const float* __restrict__ bias, float* __restrict__ out,
    int M, int L, int scatter) {
    constexpr int K = 512;
    __shared__ __align__(16) float As[32][68];
    __shared__ __align__(16) float Bs[32][68];
    const int tid = threadIdx.x;
    const int nbase = blockIdx.x * 64;
    const int mbase = blockIdx.y * 64;
    const int mloc = (tid & 15) * 4, nloc = (tid >> 4) * 4;
    float acc[4][4] = {};
    for (int k0 = 0; k0 < K; k0 += 32) {
#pragma unroll
        for (int r = 0; r < 2; ++r) {
            int f = tid + 256 * r;
            int row = f >> 3, kq = f & 7;
            int m = mbase + row;
            float4 v = make_float4(0.f, 0.f, 0.f, 0.f);
            if (m < M) v = *(const float4*)(A + (size_t)m * K + k0 + kq * 4);
            As[kq * 4 + 0][row] = v.x; As[kq * 4 + 1][row] = v.y;
            As[kq * 4 + 2][row] = v.z; As[kq * 4 + 3][row] = v.w;
        }
#pragma unroll
        for (int r = 0; r < 2; ++r) {
            int f = tid + 256 * r;
            int row = f >> 3, kq = f & 7;
            float4 v = *(const float4*)(W + (size_t)(nbase + row) * K + k0 + kq * 4);
            Bs[kq * 4 + 0][row] = v.x; Bs[kq * 4 + 1][row] = v.y;
            Bs[kq * 4 + 2][row] = v.z; Bs[kq * 4 + 3][row] = v.w;
        }
        __syncthreads();
#pragma unroll
        for (int k = 0; k < 32; ++k) {
            float4 a4 = *(const float4*)&As[k][mloc];
            float4 b4 = *(const float4*)&Bs[k][nloc];
            float av[4] = {a4.x, a4.y, a4.z, a4.w};
            float bv[4] = {b4.x, b4.y, b4.z, b4.w};
#pragma unroll
            for (int i = 0; i < 4; ++i)
#pragma unroll
                for (int j = 0; j < 4; ++j)
                    acc[i][j] += av[i] * bv[j];
        }
        __syncthreads();
    }
#pragma unroll
    for (int j = 0; j < 4; ++j) {
        const int n = nbase + nloc + j;
        const float bv = bias ? bias[n] : 0.0f;
#pragma unroll
        for (int i = 0; i < 4; ++i) {
            const int m = mbase + mloc + i;
            if (m < M) {
                size_t oidx;
                if (scatter) {
                    int bb = m / L, t = m - bb * L;
                    int hh = n >> 5, d = n & 31;
                    oidx = (((size_t)bb * Hn + hh) * L + t) * DHn + d;
                } else {
                    oidx = (size_t)m * 512 + n;
                }
                out[oidx] = acc[i][j] + bv;
            }
        }
    }
}

// ---------------------------------------------------------------------------
// Fused attention (f32, unchanged this round).
// ---------------------------------------------------------------------------
__global__ __launch_bounds__(256) void attn_kernel(
    const float* __restrict__ qw, const float* __restrict__ kw,
    const float* __restrict__ vw, const float* __restrict__ pw,
    const float* __restrict__ biasw, const float* __restrict__ maskw,
    const float* __restrict__ ub, const float* __restrict__ vb,
    float* __restrict__ ctx) {
    const int t0 = blockIdx.x * 16, h = blockIdx.y, b = blockIdx.z;
    __shared__ __align__(16) float kc[64][36];
    __shared__ __align__(16) float pc[80][36];
    __shared__ float at[16][516];
    __shared__ __align__(16) float pvp[2][16][32];
    const int tid = threadIdx.x;
    const size_t bh = (size_t)b * Hn + h;
    const float* qbase = qw + bh * Tn * DHn;
    const float* kbase = kw + bh * Tn * DHn;
    const float* vbase = vw + bh * Tn * DHn;
    const float* pbase = pw + bh * Pn * DHn;

    const int t = tid >> 4, sc = tid & 15;
    float quR[32], qvR[32];
#pragma unroll
    for (int dq = 0; dq < 8; ++dq) {
        float4 qf = *(const float4*)(qbase + (size_t)(t0 + t) * DHn + dq * 4);
        float4 uf = *(const float4*)(ub + h * DHn + dq * 4);
        float4 vf = *(const float4*)(vb + h * DHn + dq * 4);
        quR[dq * 4 + 0] = qf.x + uf.x; quR[dq * 4 + 1] = qf.y + uf.y;
        quR[dq * 4 + 2] = qf.z + uf.z; quR[dq * 4 + 3] = qf.w + uf.w;
        qvR[dq * 4 + 0] = qf.x + vf.x; qvR[dq * 4 + 1] = qf.y + vf.y;
        qvR[dq * 4 + 2] = qf.z + vf.z; qvR[dq * 4 + 3] = qf.w + vf.w;
    }
    float r[32];
    float mx = -1e30f;
    const float scale = 0.17677669529663687f;
#pragma unroll
    for (int chunk = 0; chunk < 8; ++chunk) {
        __syncthreads();
#pragma unroll
        for (int rr = 0; rr < 2; ++rr) {
            int f = tid + 256 * rr;
            int row = f >> 3, kq = f & 7;
            float4 v = *(const float4*)(kbase + (size_t)(chunk * 64 + row) * DHn + kq * 4);
            *(float4*)&kc[row][kq * 4] = v;
        }
        const int relmin = chunk * 64 + (Tn - 1) - t0 - 15;
        for (int f = tid; f < 80 * 8; f += 256) {
            int row = f >> 3, kq = f & 7;
            int pr = relmin + row; if (pr > Pn - 1) pr = Pn - 1;
            float4 v = *(const float4*)(pbase + (size_t)pr * DHn + kq * 4);
            *(float4*)&pc[row][kq * 4] = v;
        }
        __syncthreads();
#pragma unroll
        for (int so = 0; so < 4; ++so) {
            const int s_loc = sc + 16 * so;
            const int s = chunk * 64 + s_loc;
            const int pidx = s_loc + 15 - t;
            float csum = 0.f, psum = 0.f;
#pragma unroll
            for (int dq = 0; dq < 8; ++dq) {
                float4 kf = *(const float4*)&kc[s_loc][dq * 4];
                float4 pf = *(const float4*)&pc[pidx][dq * 4];
                csum += quR[dq * 4 + 0] * kf.x + quR[dq * 4 + 1] * kf.y
                      + quR[dq * 4 + 2] * kf.z + quR[dq * 4 + 3] * kf.w;
                psum += qvR[dq * 4 + 0] * pf.x + qvR[dq * 4 + 1] * pf.y
                      + qvR[dq * 4 + 2] * pf.z + qvR[dq * 4 + 3] * pf.w;
            }
            float raw = (csum + psum) * scale
                        + biasw[((size_t)b * Tn + t0 + t) * Tn + s];
            if (maskw[b * Tn + s] != 0.0f) raw = -10000.0f;
            r[chunk * 4 + so] = raw;
            mx = fmaxf(mx, raw);
        }
    }
#pragma unroll
    for (int off = 1; off < 16; off <<= 1) mx = fmaxf(mx, __shfl_xor(mx, off, 64));
    float sum = 0.f;
#pragma unroll
    for (int i = 0; i < 32; ++i) { float e = __expf(r[i] - mx); r[i] = e; sum += e; }
#pragma unroll
    for (int off = 1; off < 16; off <<= 1) sum += __shfl_xor(sum, off, 64);
    const float inv = 1.0f / sum;
#pragma unroll
    for (int chunk = 0; chunk < 8; ++chunk)
#pragma unroll
        for (int so = 0; so < 4; ++so)
            at[t][chunk * 64 + 16 * so + sc] = r[chunk * 4 + so] * inv;
    __syncthreads();
    {
        const int sq = tid >> 7, rest = tid & 127;
        const int tt = rest >> 3, dq = rest & 7;
        float4 acc = make_float4(0.f, 0.f, 0.f, 0.f);
        for (int sl = 0; sl < 256; ++sl) {
            int s = sq * 256 + sl;
            float a = at[tt][s];
            float4 v = *(const float4*)(vbase + (size_t)s * DHn + dq * 4);
            acc.x += a * v.x; acc.y += a * v.y; acc.z += a * v.z; acc.w += a * v.w;
        }
        *(float4*)&pvp[sq][tt][dq * 4] = acc;
    }
    __syncthreads();
    if (tid < 128) {
        const int tt = tid >> 3, dq = tid & 7;
        float4 a = *(const float4*)&pvp[0][tt][dq * 4];
        float4 c = *(const float4*)&pvp[1][tt][dq * 4];
        float4 o = make_float4(a.x + c.x, a.y + c.y, a.z + c.z, a.w + c.w);
        *(float4*)(ctx + (((size_t)b * Tn + t0 + tt) * Hn + h) * DHn + dq * 4) = o;
    }
}

// ---------------------------------------------------------------------------
extern "C" void kernel_launch(void* const* d_in, const int* in_sizes, int n_in,
                              void* d_out, int out_size, void* d_ws, size_t ws_size,
                              hipStream_t stream) {
    const float* query = (const float*)d_in[0];
    const float* key   = (const float*)d_in[1];
    const float* value = (const float*)d_in[2];
    const float* pos   = (const float*)d_in[3];
    const unsigned char* mask = (const unsigned char*)d_in[4];
    const float* bpp = (const float*)d_in[5];
    const float* Wq = (const float*)d_in[6];
    const float* bq = (const float*)d_in[7];
    const float* Wk = (const float*)d_in[8];
    const float* bk = (const float*)d_in[9];
    const float* Wv = (const float*)d_in[10];
    const float* bv = (const float*)d_in[11];
    const float* Wp = (const float*)d_in[12];
    const float* Wo = (const float*)d_in[13];
    const float* bo = (const float*)d_in[14];
    const float* ub = (const float*)d_in[15];
    const float* vbias = (const float*)d_in[16];
    const float* c1w = (const float*)d_in[17];
    const float* c1b = (const float*)d_in[18];
    const float* c2w = (const float*)d_in[19];
    const float* c2b = (const float*)d_in[20];

    float* ws = (float*)d_ws;
    float* q_ws    = ws;                                   // [B,H,T,DH]
    float* k_ws    = q_ws  + (size_t)Bn * Hn * Tn * DHn;
    float* v_ws    = k_ws  + (size_t)Bn * Hn * Tn * DHn;
    float* p_ws    = v_ws  + (size_t)Bn * Hn * Tn * DHn;   // [B,H,P,DH]
    float* bias_ws = p_ws  + (size_t)Bn * Hn * Pn * DHn;   // [B,T,T]
    float* ctx_ws  = bias_ws + (size_t)Bn * Tn * Tn;       // [B,T,H,DH]
    float* mask_ws = ctx_ws + (size_t)Bn * Tn * Dn;        // [B,T]
    float* f32_end = mask_ws + Bn * Tn;

    const size_t actN = (size_t)Bn * Pn * Dn;              // largest activation (pos)
    const size_t wN   = (size_t)Dn * Dn;
    unsigned short* act_hi = (unsigned short*)f32_end;
    unsigned short* act_lo = act_hi + actN;
    unsigned short* w_hi   = act_lo + actN;
    unsigned short* w_lo   = w_hi + wN;
    const size_t needed_bytes = (size_t)((char*)(w_lo + wN) - (char*)d_ws);
    const bool use_mfma = ws_size >= needed_bytes;

    mask_decode_kernel<<<dim3(1), dim3(256), 0, stream>>>(mask, mask_ws);
    conv_bias_kernel<<<dim3(16, 16, Bn), dim3(256), 0, stream>>>(
        bpp, c1w, c1b, c2w, c2b, bias_ws);

    const int qkvN4 = Bn * Tn * Dn / 4;      // 1,048,576
    const int posN4 = (int)(actN / 4);       // 2,095,104
    const int wN4   = (int)(wN / 4);         // 65,536
    const int cgrid = 2048, wgrid = 256;

    if (use_mfma) {
        // Q
        split_bf16_kernel<<<dim3(wgrid), dim3(256), 0, stream>>>(Wq, w_hi, w_lo, wN4);
        split_bf16_kernel<<<dim3(cgrid), dim3(256), 0, stream>>>(query, act_hi, act_lo, qkvN4);
        gemm_mfma_split_kernel<<<dim3(4, 64), dim3(256), 0, stream>>>(
            act_hi, act_lo, w_hi, w_lo, bq, q_ws, Bn * Tn, Tn, 1);
        // K
        split_bf16_kernel<<<dim3(wgrid), dim3(256), 0, stream>>>(Wk, w_hi, w_lo, wN4);
        split_bf16_kernel<<<dim3(cgrid), dim3(256), 0, stream>>>(key, act_hi, act_lo, qkvN4);
        gemm_mfma_split_kernel<<<dim3(4, 64), dim3(256), 0, stream>>>(
            act_hi, act_lo, w_hi, w_lo, bk, k_ws, Bn * Tn, Tn, 1);
        // V
        split_bf16_kernel<<<dim3(wgrid), dim3(256), 0, stream>>>(Wv, w_hi, w_lo, wN4);
        split_bf16_kernel<<<dim3(cgrid), dim3(256), 0, stream>>>(value, act_hi, act_lo, qkvN4);
        gemm_mfma_split_kernel<<<dim3(4, 64), dim3(256), 0, stream>>>(
            act_hi, act_lo, w_hi, w_lo, bv, v_ws, Bn * Tn, Tn, 1);
        // P
        split_bf16_kernel<<<dim3(wgrid), dim3(256), 0, stream>>>(Wp, w_hi, w_lo, wN4);
        split_bf16_kernel<<<dim3(cgrid), dim3(256), 0, stream>>>(pos, act_hi, act_lo, posN4);
        gemm_mfma_split_kernel<<<dim3(4, 128), dim3(256), 0, stream>>>(
            act_hi, act_lo, w_hi, w_lo, (const float*)nullptr, p_ws, Bn * Pn, Pn, 1);
    } else {
        gemm_f32_kernel<<<dim3(8, 128), dim3(256), 0, stream>>>(
            query, Wq, bq, q_ws, Bn * Tn, Tn, 1);
        gemm_f32_kernel<<<dim3(8, 128), dim3(256), 0, stream>>>(
            key, Wk, bk, k_ws, Bn * Tn, Tn, 1);
        gemm_f32_kernel<<<dim3(8, 128), dim3(256), 0, stream>>>(
            value, Wv, bv, v_ws, Bn * Tn, Tn, 1);
        gemm_f32_kernel<<<dim3(8, 256), dim3(256), 0, stream>>>(
            pos, Wp, (const float*)nullptr, p_ws, Bn * Pn, Pn, 1);
    }

    attn_kernel<<<dim3(Tn / 16, Hn, Bn), dim3(256), 0, stream>>>(
        q_ws, k_ws, v_ws, p_ws, bias_ws, mask_ws, ub, vbias, ctx_ws);

    if (use_mfma) {
        split_bf16_kernel<<<dim3(wgrid), dim3(256), 0, stream>>>(Wo, w_hi, w_lo, wN4);
        split_bf16_kernel<<<dim3(cgrid), dim3(256), 0, stream>>>(ctx_ws, act_hi, act_lo, qkvN4);
        gemm_mfma_split_kernel<<<dim3(4, 64), dim3(256), 0, stream>>>(
            act_hi, act_lo, w_hi, w_lo, bo, (float*)d_out, Bn * Tn, Tn, 0);
    } else {
        gemm_f32_kernel<<<dim3(8, 128), dim3(256), 0, stream>>>(
            ctx_ws, Wo, bo, (float*)d_out, Bn * Tn, Tn, 0);
    }
}

// Round 3
// 612.560 us; speedup vs baseline: 1.8331x; 1.5241x over previous
//
#include <hip/hip_runtime.h>

constexpr int Bn  = 16;
constexpr int Tn  = 512;
constexpr int Dn  = 512;
constexpr int Hn  = 16;
constexpr int DHn = 32;
constexpr int Pn  = 1023;   // 2T-1

typedef __attribute__((ext_vector_type(8))) short s16x8;
typedef __attribute__((ext_vector_type(4))) float f32x4;

__device__ __forceinline__ unsigned short f2bf(float x) {
    unsigned u = __float_as_uint(x);
    unsigned r = u + 0x7fff + ((u >> 16) & 1);
    return (unsigned short)(r >> 16);
}
__device__ __forceinline__ float bf2f(unsigned short h) {
    return __uint_as_float(((unsigned)h) << 16);
}

__device__ __forceinline__ f32x4 mfma3(s16x8 ah, s16x8 al, s16x8 bh2, s16x8 bl, f32x4 c) {
    c = __builtin_amdgcn_mfma_f32_16x16x32_bf16(ah, bh2, c, 0, 0, 0);
    c = __builtin_amdgcn_mfma_f32_16x16x32_bf16(ah, bl,  c, 0, 0, 0);
    c = __builtin_amdgcn_mfma_f32_16x16x32_bf16(al, bh2, c, 0, 0, 0);
    return c;
}

// ---------------------------------------------------------------------------
// Split f32 -> (hi, lo) bf16 planes (used for the 512x512 weights only).
// ---------------------------------------------------------------------------
__global__ __launch_bounds__(256) void split_bf16_kernel(
    const float* __restrict__ in, unsigned short* __restrict__ hi,
    unsigned short* __restrict__ lo, int n4) {
    for (int i = blockIdx.x * 256 + threadIdx.x; i < n4; i += gridDim.x * 256) {
        float4 v = ((const float4*)in)[i];
        ushort4 h, l;
        h.x = f2bf(v.x); l.x = f2bf(v.x - bf2f(h.x));
        h.y = f2bf(v.y); l.y = f2bf(v.y - bf2f(h.y));
        h.z = f2bf(v.z); l.z = f2bf(v.z - bf2f(h.z));
        h.w = f2bf(v.w); l.w = f2bf(v.w - bf2f(h.w));
        ((ushort4*)hi)[i] = h;
        ((ushort4*)lo)[i] = l;
    }
}

// ---------------------------------------------------------------------------
// Mask decode: detect layout (int32 / byte-bool / float32) then write 0/1 flags
// ---------------------------------------------------------------------------
__global__ void mask_decode_kernel(const unsigned char* __restrict__ mraw,
                                   float* __restrict__ mout) {
    __shared__ int s_nonmod4;
    __shared__ int s_big;
    if (threadIdx.x == 0) { s_nonmod4 = 0; s_big = 0; }
    __syncthreads();
    int f0 = 0, f1 = 0;
    for (int i = threadIdx.x; i < Bn * Tn; i += 256) {
        unsigned char v = mraw[i];
        if ((i & 3) != 0 && v != 0) f0 = 1;
        if (v > 1) f1 = 1;
    }
    if (f0) atomicOr(&s_nonmod4, 1);
    if (f1) atomicOr(&s_big, 1);
    __syncthreads();
    const int layout = s_big ? 2 : (s_nonmod4 ? 1 : 0);
    for (int i = threadIdx.x; i < Bn * Tn; i += 256) {
        bool m;
        if (layout == 2)      m = ((const float*)mraw)[i] != 0.0f;
        else if (layout == 1) m = mraw[i] != 0;
        else                  m = ((const int*)mraw)[i] != 0;
        mout[i] = m ? 1.0f : 0.0f;
    }
}

// ---------------------------------------------------------------------------
// Fused conv bias: bpp_bias = conv2(relu(conv1(bpp))), 3x3 SAME, 1->16->1 ch.
// ---------------------------------------------------------------------------
__global__ __launch_bounds__(256) void conv_bias_kernel(
    const float* __restrict__ bpp, const float* __restrict__ c1w,
    const float* __restrict__ c1b, const float* __restrict__ c2w,
    const float* __restrict__ c2b, float* __restrict__ biasout) {
    const int x0 = blockIdx.x * 32, y0 = blockIdx.y * 32, b = blockIdx.z;
    __shared__ float inb[36][37];
    __shared__ float h1c[2][34][35];
    __shared__ float w1[16][9], w2[16][9], b1[16];
    const int tid = threadIdx.x;
    if (tid < 144) { w1[tid / 9][tid % 9] = c1w[tid]; w2[tid / 9][tid % 9] = c2w[tid]; }
    if (tid < 16) b1[tid] = c1b[tid];
    const float* src = bpp + (size_t)b * Tn * Tn;
    for (int i = tid; i < 36 * 36; i += 256) {
        int yy = i / 36, xx = i % 36;
        int ya = y0 - 2 + yy, xa = x0 - 2 + xx;
        float v = 0.0f;
        if (ya >= 0 && ya < Tn && xa >= 0 && xa < Tn) v = src[(size_t)ya * Tn + xa];
        inb[yy][xx] = v;
    }
    __syncthreads();
    float acc[4] = {0.f, 0.f, 0.f, 0.f};
    for (int ch = 0; ch < 16; ++ch) {
        const int buf = ch & 1;
        for (int i = tid; i < 34 * 34; i += 256) {
            int yy = i / 34, xx = i % 34;
            int ya = y0 - 1 + yy, xa = x0 - 1 + xx;
            float v = 0.0f;
            if (ya >= 0 && ya < Tn && xa >= 0 && xa < Tn) {
                float s = b1[ch];
#pragma unroll
                for (int dy = 0; dy < 3; ++dy)
#pragma unroll
                    for (int dx = 0; dx < 3; ++dx)
                        s += inb[yy + dy][xx + dx] * w1[ch][dy * 3 + dx];
                v = fmaxf(s, 0.0f);
            }
            h1c[buf][yy][xx] = v;
        }
        __syncthreads();
#pragma unroll
        for (int r = 0; r < 4; ++r) {
            int o = tid + 256 * r;
            int oy = o >> 5, ox = o & 31;
            float s = 0.0f;
#pragma unroll
            for (int dy = 0; dy < 3; ++dy)
#pragma unroll
                for (int dx = 0; dx < 3; ++dx)
                    s += h1c[buf][oy + dy][ox + dx] * w2[ch][dy * 3 + dx];
            acc[r] += s;
        }
    }
    const float ob = c2b[0];
#pragma unroll
    for (int r = 0; r < 4; ++r) {
        int o = tid + 256 * r;
        int oy = o >> 5, ox = o & 31;
        biasout[((size_t)b * Tn + y0 + oy) * Tn + (x0 + ox)] = acc[r] + ob;
    }
}

// ---------------------------------------------------------------------------
// Split-bf16 MFMA GEMM: out = A @ W^T (+bias). A:[M,512] f32 (split on the
// fly during staging). W pre-split planes. 128x128 tile, BK=32, 4 waves.
// mode 0: f32 [M,512]; mode 1: f32 scatter [b,h,t,d];
// mode 2: bf16 hi/lo planes [b,h,t,d]; mode 3: bf16 hi/lo planes [b,h,d,t].
// ---------------------------------------------------------------------------
__global__ __launch_bounds__(256) void gemm_mfma_kernel(
    const float* __restrict__ A,
    const unsigned short* __restrict__ Wh, const unsigned short* __restrict__ Wl,
    const float* __restrict__ bias, float* __restrict__ outf,
    unsigned short* __restrict__ out_hi, unsigned short* __restrict__ out_lo,
    int M, int L, int mode) {
    constexpr int K = 512, BK = 32, LDT = 40;
    __shared__ __align__(16) unsigned short AhT[128 * LDT];
    __shared__ __align__(16) unsigned short AlT[128 * LDT];
    __shared__ __align__(16) unsigned short WhT[128 * LDT];
    __shared__ __align__(16) unsigned short WlT[128 * LDT];
    const int tid = threadIdx.x;
    const int nbase = blockIdx.x * 128, mbase = blockIdx.y * 128;
    const int wave = tid >> 6, lane = tid & 63;
    const int wr = wave >> 1, wc = wave & 1;
    const int lg = lane >> 4, lr = lane & 15;
    f32x4 acc[4][4] = {};
    for (int k0 = 0; k0 < K; k0 += BK) {
        __syncthreads();
#pragma unroll
        for (int c = 0; c < 2; ++c) {
            const int idx = tid + 256 * c;
            const int r = idx >> 2, cb = (idx & 3) * 8;
            int gm = mbase + r; if (gm >= M) gm = M - 1;
            const float* ap = A + (size_t)gm * K + k0 + cb;
            float4 a0 = *(const float4*)ap;
            float4 a1 = *(const float4*)(ap + 4);
            float av[8] = {a0.x, a0.y, a0.z, a0.w, a1.x, a1.y, a1.z, a1.w};
            s16x8 hh, ll;
#pragma unroll
            for (int j = 0; j < 8; ++j) {
                unsigned short x = f2bf(av[j]);
                hh[j] = (short)x;
                ll[j] = (short)f2bf(av[j] - bf2f(x));
            }
            const int loff = r * LDT + cb;
            *(s16x8*)&AhT[loff] = hh;
            *(s16x8*)&AlT[loff] = ll;
            const size_t gw = (size_t)(nbase + r) * K + k0 + cb;
            *(s16x8*)&WhT[loff] = *(const s16x8*)&Wh[gw];
            *(s16x8*)&WlT[loff] = *(const s16x8*)&Wl[gw];
        }
        __syncthreads();
        s16x8 wh[4], wl[4];
#pragma unroll
        for (int nj = 0; nj < 4; ++nj) {
            const int off = (wc * 64 + nj * 16 + lr) * LDT + lg * 8;
            wh[nj] = *(const s16x8*)&WhT[off];
            wl[nj] = *(const s16x8*)&WlT[off];
        }
#pragma unroll
        for (int mi = 0; mi < 4; ++mi) {
            const int off = (wr * 64 + mi * 16 + lr) * LDT + lg * 8;
            s16x8 ah = *(const s16x8*)&AhT[off];
            s16x8 al = *(const s16x8*)&AlT[off];
#pragma unroll
            for (int nj = 0; nj < 4; ++nj)
                acc[mi][nj] = __builtin_amdgcn_mfma_f32_16x16x32_bf16(ah, wh[nj], acc[mi][nj], 0, 0, 0);
#pragma unroll
            for (int nj = 0; nj < 4; ++nj)
                acc[mi][nj] = __builtin_amdgcn_mfma_f32_16x16x32_bf16(ah, wl[nj], acc[mi][nj], 0, 0, 0);
#pragma unroll
            for (int nj = 0; nj < 4; ++nj)
                acc[mi][nj] = __builtin_amdgcn_mfma_f32_16x16x32_bf16(al, wh[nj], acc[mi][nj], 0, 0, 0);
        }
    }
#pragma unroll
    for (int nj = 0; nj < 4; ++nj) {
        const int n = nbase + wc * 64 + nj * 16 + lr;
        const float bv = bias ? bias[n] : 0.0f;
#pragma unroll
        for (int mi = 0; mi < 4; ++mi) {
#pragma unroll
            for (int r2 = 0; r2 < 4; ++r2) {
                const int m = mbase + wr * 64 + mi * 16 + lg * 4 + r2;
                if (m < M) {
                    const float v = acc[mi][nj][r2] + bv;
                    if (mode == 0) {
                        outf[(size_t)m * 512 + n] = v;
                    } else if (mode == 1) {
                        int bb = m / L, t = m - bb * L;
                        int hh2 = n >> 5, d = n & 31;
                        outf[(((size_t)bb * Hn + hh2) * L + t) * DHn + d] = v;
                    } else {
                        int bb = m / L, t = m - bb * L;
                        int hh2 = n >> 5, d = n & 31;
                        size_t oidx = (mode == 2)
                            ? ((((size_t)bb * Hn + hh2) * L + t) * DHn + d)
                            : ((((size_t)bb * Hn + hh2) * DHn + d) * L + t);
                        unsigned short hi16 = f2bf(v);
                        out_hi[oidx] = hi16;
                        out_lo[oidx] = f2bf(v - bf2f(hi16));
                    }
                }
            }
        }
    }
}

// ---------------------------------------------------------------------------
// MFMA fused attention. Grid (T/32, H, B), 256 threads = 4 waves.
// Wave w owns s in [128w, 128w+128). Scores in registers (16 16x16 tiles).
// Pos path: rolling MFMA tiles + lane-shuffle relative shift.
// ---------------------------------------------------------------------------
__global__ __launch_bounds__(256, 2) void attn_mfma_kernel(
    const float* __restrict__ q_ws,
    const unsigned short* __restrict__ k_hi, const unsigned short* __restrict__ k_lo,
    const unsigned short* __restrict__ vt_hi, const unsigned short* __restrict__ vt_lo,
    const unsigned short* __restrict__ p_hi, const unsigned short* __restrict__ p_lo,
    const float* __restrict__ biasw, const float* __restrict__ maskw,
    const float* __restrict__ ub, const float* __restrict__ vb,
    float* __restrict__ ctx) {
    const int t0 = blockIdx.x * 32, h = blockIdx.y, b = blockIdx.z;
    const int tid = threadIdx.x;
    const int w = tid >> 6, l = tid & 63;
    const int lr = l & 15, lg = l >> 4;
    const size_t bh = (size_t)b * Hn + h;
    const int pbase = 480 - t0;
    const float scale = 0.17677669529663687f;  // 1/sqrt(32)

    __shared__ unsigned short attn_hi_l[4][32 * 64];
    __shared__ unsigned short attn_lo_l[4][32 * 64];
    __shared__ float ctxred[4][32][36];
    __shared__ float redbuf[2][32][4];

    // ---- Q fragments (hi/lo split, +u and +v) ----
    s16x8 quh[2], qul[2], qvh[2], qvl[2];
#pragma unroll
    for (int i = 0; i < 2; ++i) {
        const float* qrow = q_ws + (bh * Tn + t0 + 16 * i + lr) * DHn + lg * 8;
        float4 qa = *(const float4*)qrow;
        float4 qb = *(const float4*)(qrow + 4);
        float qv8[8] = {qa.x, qa.y, qa.z, qa.w, qb.x, qb.y, qb.z, qb.w};
#pragma unroll
        for (int j = 0; j < 8; ++j) {
            const float uj = ub[h * DHn + lg * 8 + j];
            const float vj = vb[h * DHn + lg * 8 + j];
            float xu = qv8[j] + uj;
            unsigned short hu = f2bf(xu);
            quh[i][j] = (short)hu; qul[i][j] = (short)f2bf(xu - bf2f(hu));
            float xv = qv8[j] + vj;
            unsigned short hv = f2bf(xv);
            qvh[i][j] = (short)hv; qvl[i][j] = (short)f2bf(xv - bf2f(hv));
        }
    }
    // mask flags per m-tile (depend only on lr)
    float mv[8];
#pragma unroll
    for (int m = 0; m < 8; ++m)
        mv[m] = maskw[b * Tn + w * 128 + m * 16 + lr];

    // pos tile compute: B = P rows [pbase + 128w + 16jt + lr]
    auto posTile = [&](int i, int jt) -> f32x4 {
        int pidx = pbase + w * 128 + jt * 16 + lr;
        if (pidx > Pn - 1) pidx = Pn - 1;
        const size_t po = (bh * Pn + pidx) * DHn + lg * 8;
        s16x8 ph = *(const s16x8*)(p_hi + po);
        s16x8 pl = *(const s16x8*)(p_lo + po);
        f32x4 t = {0.f, 0.f, 0.f, 0.f};
        return mfma3(qvh[i], qvl[i], ph, pl, t);
    };

    f32x4 sc[2][8];
    f32x4 p0a = posTile(0, 1);
    f32x4 p1a = posTile(1, 0);
    const int ubase = lr - 4 * lg + 31;

#pragma unroll
    for (int m = 0; m < 8; ++m) {
        f32x4 p0b = posTile(0, m + 2);
        f32x4 p1b = posTile(1, m + 1);
        // bias loads
        float bvls[2][4];
#pragma unroll
        for (int i2 = 0; i2 < 2; ++i2)
#pragma unroll
            for (int r2 = 0; r2 < 4; ++r2)
                bvls[i2][r2] = biasw[((size_t)b * Tn + t0 + 16 * i2 + 4 * lg + r2) * Tn
                                     + w * 128 + m * 16 + lr];
        // content K frags
        const size_t ko = (bh * Tn + w * 128 + m * 16 + lr) * DHn + lg * 8;
        s16x8 kh = *(const s16x8*)(k_hi + ko);
        s16x8 kl = *(const s16x8*)(k_lo + ko);
#pragma unroll
        for (int i = 0; i < 2; ++i) {
            f32x4 c = {0.f, 0.f, 0.f, 0.f};
            c = mfma3(quh[i], qul[i], kh, kl, c);
            f32x4 Pa = (i == 0) ? p0a : p1a;
            f32x4 Pb = (i == 0) ? p0b : p1b;
            f32x4 out;
#pragma unroll
            for (int r2 = 0; r2 < 4; ++r2) {
                const int u = ubase - r2;
                const int src = (l & 48) | (u & 15);
                float pa = __shfl(Pa[r2], src, 64);
                float pb = __shfl(Pb[r2], src, 64);
                float pv = (u < 32) ? pa : pb;
                float v = (c[r2] + pv) * scale + bvls[i][r2];
                if (mv[m] != 0.0f) v = -10000.0f;
                out[r2] = v;
            }
            sc[i][m] = out;
        }
        p0a = p0b; p1a = p1b;
    }

    // ---- softmax ----
    float rowm[2][4], inv[2][4];
#pragma unroll
    for (int i = 0; i < 2; ++i)
#pragma unroll
        for (int r2 = 0; r2 < 4; ++r2) {
            float mx = -1e30f;
#pragma unroll
            for (int m = 0; m < 8; ++m) mx = fmaxf(mx, sc[i][m][r2]);
#pragma unroll
            for (int off = 1; off < 16; off <<= 1) mx = fmaxf(mx, __shfl_xor(mx, off, 64));
            if (lr == 0) redbuf[0][16 * i + 4 * lg + r2][w] = mx;
        }
    __syncthreads();
#pragma unroll
    for (int i = 0; i < 2; ++i)
#pragma unroll
        for (int r2 = 0; r2 < 4; ++r2) {
            float4 mm = *(const float4*)redbuf[0][16 * i + 4 * lg + r2];
            rowm[i][r2] = fmaxf(fmaxf(mm.x, mm.y), fmaxf(mm.z, mm.w));
        }
    float psum[2][4] = {};
#pragma unroll
    for (int i = 0; i < 2; ++i)
#pragma unroll
        for (int m = 0; m < 8; ++m)
#pragma unroll
            for (int r2 = 0; r2 < 4; ++r2) {
                float e = __expf(sc[i][m][r2] - rowm[i][r2]);
                sc[i][m][r2] = e;
                psum[i][r2] += e;
            }
#pragma unroll
    for (int i = 0; i < 2; ++i)
#pragma unroll
        for (int r2 = 0; r2 < 4; ++r2) {
            float s = psum[i][r2];
#pragma unroll
            for (int off = 1; off < 16; off <<= 1) s += __shfl_xor(s, off, 64);
            if (lr == 0) redbuf[1][16 * i + 4 * lg + r2][w] = s;
        }
    __syncthreads();
#pragma unroll
    for (int i = 0; i < 2; ++i)
#pragma unroll
        for (int r2 = 0; r2 < 4; ++r2) {
            float4 ss = *(const float4*)redbuf[1][16 * i + 4 * lg + r2];
            inv[i][r2] = 1.0f / (ss.x + ss.y + ss.z + ss.w);
        }

    // ---- PV (two s-halves of 64, attn staged in LDS, XOR-swizzled) ----
    f32x4 cacc[2][2] = {};
#pragma unroll
    for (int sh = 0; sh < 2; ++sh) {
        __syncthreads();
#pragma unroll
        for (int mm2 = 0; mm2 < 4; ++mm2) {
            const int m = sh * 4 + mm2;
#pragma unroll
            for (int i = 0; i < 2; ++i)
#pragma unroll
                for (int r2 = 0; r2 < 4; ++r2) {
                    const int trow = 16 * i + 4 * lg + r2;
                    float a = sc[i][m][r2] * inv[i][r2];
                    unsigned short ah16 = f2bf(a);
                    unsigned short al16 = f2bf(a - bf2f(ah16));
                    const int cbyte = (mm2 * 16 + lr) * 2;
                    const int off = trow * 128 + (cbyte ^ ((trow & 7) << 4));
                    *(unsigned short*)((char*)attn_hi_l[w] + off) = ah16;
                    *(unsigned short*)((char*)attn_lo_l[w] + off) = al16;
                }
        }
        __syncthreads();
#pragma unroll
        for (int ks = 0; ks < 2; ++ks) {
            s16x8 pah[2], pal[2];
#pragma unroll
            for (int i = 0; i < 2; ++i) {
                const int trow = 16 * i + lr;
                const int cbyte = ks * 64 + lg * 16;
                const int off = trow * 128 + (cbyte ^ ((trow & 7) << 4));
                pah[i] = *(const s16x8*)((char*)attn_hi_l[w] + off);
                pal[i] = *(const s16x8*)((char*)attn_lo_l[w] + off);
            }
#pragma unroll
            for (int n = 0; n < 2; ++n) {
                const int sg = w * 128 + sh * 64 + ks * 32 + lg * 8;
                const size_t vo = (bh * DHn + n * 16 + lr) * Tn + sg;
                s16x8 vh = *(const s16x8*)(vt_hi + vo);
                s16x8 vl = *(const s16x8*)(vt_lo + vo);
#pragma unroll
                for (int i = 0; i < 2; ++i)
                    cacc[i][n] = mfma3(pah[i], pal[i], vh, vl, cacc[i][n]);
            }
        }
    }

    // ---- cross-wave reduction + store ----
#pragma unroll
    for (int i = 0; i < 2; ++i)
#pragma unroll
        for (int n = 0; n < 2; ++n)
#pragma unroll
            for (int r2 = 0; r2 < 4; ++r2)
                ctxred[w][16 * i + 4 * lg + r2][n * 16 + lr] = cacc[i][n][r2];
    __syncthreads();
    {
        const int trow = tid >> 3, d0 = (tid & 7) * 4;
        float4 s0 = *(const float4*)&ctxred[0][trow][d0];
        float4 s1 = *(const float4*)&ctxred[1][trow][d0];
        float4 s2 = *(const float4*)&ctxred[2][trow][d0];
        float4 s3 = *(const float4*)&ctxred[3][trow][d0];
        float4 o = make_float4(s0.x + s1.x + s2.x + s3.x, s0.y + s1.y + s2.y + s3.y,
                               s0.z + s1.z + s2.z + s3.z, s0.w + s1.w + s2.w + s3.w);
        *(float4*)(ctx + ((size_t)b * Tn + t0 + trow) * Dn + h * DHn + d0) = o;
    }
}

// ---------------------------------------------------------------------------
extern "C" void kernel_launch(void* const* d_in, const int* in_sizes, int n_in,
                              void* d_out, int out_size, void* d_ws, size_t ws_size,
                              hipStream_t stream) {
    const float* query = (const float*)d_in[0];
    const float* key   = (const float*)d_in[1];
    const float* value = (const float*)d_in[2];
    const float* pos   = (const float*)d_in[3];
    const unsigned char* mask = (const unsigned char*)d_in[4];
    const float* bpp = (const float*)d_in[5];
    const float* Wq = (const float*)d_in[6];
    const float* bq = (const float*)d_in[7];
    const float* Wk = (const float*)d_in[8];
    const float* bk = (const float*)d_in[9];
    const float* Wv = (const float*)d_in[10];
    const float* bv = (const float*)d_in[11];
    const float* Wp = (const float*)d_in[12];
    const float* Wo = (const float*)d_in[13];
    const float* bo = (const float*)d_in[14];
    const float* ub = (const float*)d_in[15];
    const float* vbias = (const float*)d_in[16];
    const float* c1w = (const float*)d_in[17];
    const float* c1b = (const float*)d_in[18];
    const float* c2w = (const float*)d_in[19];
    const float* c2b = (const float*)d_in[20];

    const size_t qkvE = (size_t)Bn * Hn * Tn * DHn;   // 4.19M
    const size_t posE = (size_t)Bn * Hn * Pn * DHn;   // 8.38M

    float* ws = (float*)d_ws;
    float* bias_ws = ws;                                // [B,T,T]
    float* mask_ws = bias_ws + (size_t)Bn * Tn * Tn;    // [B,T]
    float* q_ws    = mask_ws + Bn * Tn;                 // [B,H,T,DH] f32
    float* ctx_ws  = q_ws + qkvE;                       // [B,T,D] f32
    unsigned short* k_hi = (unsigned short*)(ctx_ws + (size_t)Bn * Tn * Dn);
    unsigned short* k_lo = k_hi + qkvE;
    unsigned short* v_hi = k_lo + qkvE;                 // transposed [B,H,DH,T]
    unsigned short* v_lo = v_hi + qkvE;
    unsigned short* p_hi = v_lo + qkvE;                 // [B,H,P,DH]
    unsigned short* p_lo = p_hi + posE;
    unsigned short* w_hi = p_lo + posE;
    unsigned short* w_lo = w_hi + (size_t)Dn * Dn;

    const int wN4 = Dn * Dn / 4;

    mask_decode_kernel<<<dim3(1), dim3(256), 0, stream>>>(mask, mask_ws);
    conv_bias_kernel<<<dim3(16, 16, Bn), dim3(256), 0, stream>>>(
        bpp, c1w, c1b, c2w, c2b, bias_ws);

    // Q (f32 scatter)
    split_bf16_kernel<<<dim3(256), dim3(256), 0, stream>>>(Wq, w_hi, w_lo, wN4);
    gemm_mfma_kernel<<<dim3(4, 64), dim3(256), 0, stream>>>(
        query, w_hi, w_lo, bq, q_ws, nullptr, nullptr, Bn * Tn, Tn, 1);
    // K (bf16 planes)
    split_bf16_kernel<<<dim3(256), dim3(256), 0, stream>>>(Wk, w_hi, w_lo, wN4);
    gemm_mfma_kernel<<<dim3(4, 64), dim3(256), 0, stream>>>(
        key, w_hi, w_lo, bk, nullptr, k_hi, k_lo, Bn * Tn, Tn, 2);
    // V (bf16 planes, transposed)
    split_bf16_kernel<<<dim3(256), dim3(256), 0, stream>>>(Wv, w_hi, w_lo, wN4);
    gemm_mfma_kernel<<<dim3(4, 64), dim3(256), 0, stream>>>(
        value, w_hi, w_lo, bv, nullptr, v_hi, v_lo, Bn * Tn, Tn, 3);
    // P (bf16 planes)
    split_bf16_kernel<<<dim3(256), dim3(256), 0, stream>>>(Wp, w_hi, w_lo, wN4);
    gemm_mfma_kernel<<<dim3(4, 128), dim3(256), 0, stream>>>(
        pos, w_hi, w_lo, nullptr, nullptr, p_hi, p_lo, Bn * Pn, Pn, 2);

    attn_mfma_kernel<<<dim3(Tn / 32, Hn, Bn), dim3(256), 0, stream>>>(
        q_ws, k_hi, k_lo, v_hi, v_lo, p_hi, p_lo, bias_ws, mask_ws, ub, vbias, ctx_ws);

    // Output projection
    split_bf16_kernel<<<dim3(256), dim3(256), 0, stream>>>(Wo, w_hi, w_lo, wN4);
    gemm_mfma_kernel<<<dim3(4, 64), dim3(256), 0, stream>>>(
        ctx_ws, w_hi, w_lo, bo, (float*)d_out, nullptr, nullptr, Bn * Tn, Tn, 0);
}

// Round 4
// 520.084 us; speedup vs baseline: 2.1591x; 1.1778x over previous
//
#include <hip/hip_runtime.h>

constexpr int Bn  = 16;
constexpr int Tn  = 512;
constexpr int Dn  = 512;
constexpr int Hn  = 16;
constexpr int DHn = 32;
constexpr int Pn  = 1023;   // 2T-1

typedef __attribute__((ext_vector_type(8))) short s16x8;
typedef __attribute__((ext_vector_type(4))) float f32x4;

__device__ __forceinline__ unsigned short f2bf(float x) {
    unsigned u = __float_as_uint(x);
    unsigned r = u + 0x7fff + ((u >> 16) & 1);
    return (unsigned short)(r >> 16);
}
__device__ __forceinline__ float bf2f(unsigned short h) {
    return __uint_as_float(((unsigned)h) << 16);
}

__device__ __forceinline__ f32x4 mfma3(s16x8 ah, s16x8 al, s16x8 bh2, s16x8 bl, f32x4 c) {
    c = __builtin_amdgcn_mfma_f32_16x16x32_bf16(ah, bh2, c, 0, 0, 0);
    c = __builtin_amdgcn_mfma_f32_16x16x32_bf16(ah, bl,  c, 0, 0, 0);
    c = __builtin_amdgcn_mfma_f32_16x16x32_bf16(al, bh2, c, 0, 0, 0);
    return c;
}

// ---------------------------------------------------------------------------
// Split all 5 weight matrices (512x512 each) in one dispatch. grid (64, 5).
// ---------------------------------------------------------------------------
__global__ __launch_bounds__(256) void split_weights_kernel(
    const float* __restrict__ w0, const float* __restrict__ w1,
    const float* __restrict__ w2, const float* __restrict__ w3,
    const float* __restrict__ w4,
    unsigned short* __restrict__ hi, unsigned short* __restrict__ lo) {
    const float* srcs[5] = {w0, w1, w2, w3, w4};
    const float* src = srcs[blockIdx.y];
    const size_t off = (size_t)blockIdx.y * Dn * Dn;
    unsigned short* h = hi + off;
    unsigned short* l = lo + off;
    const int n4 = Dn * Dn / 4;
    for (int i = blockIdx.x * 256 + threadIdx.x; i < n4; i += 64 * 256) {
        float4 v = ((const float4*)src)[i];
        ushort4 hh, ll;
        hh.x = f2bf(v.x); ll.x = f2bf(v.x - bf2f(hh.x));
        hh.y = f2bf(v.y); ll.y = f2bf(v.y - bf2f(hh.y));
        hh.z = f2bf(v.z); ll.z = f2bf(v.z - bf2f(hh.z));
        hh.w = f2bf(v.w); ll.w = f2bf(v.w - bf2f(hh.w));
        ((ushort4*)h)[i] = hh;
        ((ushort4*)l)[i] = ll;
    }
}

// ---------------------------------------------------------------------------
// Mask decode: detect layout (int32 / byte-bool / float32) then write 0/1 flags
// ---------------------------------------------------------------------------
__global__ void mask_decode_kernel(const unsigned char* __restrict__ mraw,
                                   float* __restrict__ mout) {
    __shared__ int s_nonmod4;
    __shared__ int s_big;
    if (threadIdx.x == 0) { s_nonmod4 = 0; s_big = 0; }
    __syncthreads();
    int f0 = 0, f1 = 0;
    for (int i = threadIdx.x; i < Bn * Tn; i += 256) {
        unsigned char v = mraw[i];
        if ((i & 3) != 0 && v != 0) f0 = 1;
        if (v > 1) f1 = 1;
    }
    if (f0) atomicOr(&s_nonmod4, 1);
    if (f1) atomicOr(&s_big, 1);
    __syncthreads();
    const int layout = s_big ? 2 : (s_nonmod4 ? 1 : 0);
    for (int i = threadIdx.x; i < Bn * Tn; i += 256) {
        bool m;
        if (layout == 2)      m = ((const float*)mraw)[i] != 0.0f;
        else if (layout == 1) m = mraw[i] != 0;
        else                  m = ((const int*)mraw)[i] != 0;
        mout[i] = m ? 1.0f : 0.0f;
    }
}

// ---------------------------------------------------------------------------
// Fused conv bias: bpp_bias = conv2(relu(conv1(bpp))), 3x3 SAME, 1->16->1 ch.
// 64x64 output tile per block; register-tiled 4x4 per thread; vector LDS ops.
// ---------------------------------------------------------------------------
__global__ __launch_bounds__(256) void conv_bias_kernel(
    const float* __restrict__ bpp, const float* __restrict__ c1w,
    const float* __restrict__ c1b, const float* __restrict__ c2w,
    const float* __restrict__ c2b, float* __restrict__ biasout) {
    const int x0 = blockIdx.x * 64, y0 = blockIdx.y * 64, b = blockIdx.z;
    __shared__ __align__(16) float inb[68][72];  // rows y0-2.., cols x0-4..
    __shared__ __align__(16) float h1[66][72];   // h1 logical (r-1, c-1) at [r][c]
    __shared__ float w1s[16][9], w2s[16][9], b1s[16];
    const int tid = threadIdx.x;
    const int tx = tid & 15, ty = tid >> 4;

    if (tid < 144) { w1s[tid / 9][tid % 9] = c1w[tid]; w2s[tid / 9][tid % 9] = c2w[tid]; }
    if (tid < 16) b1s[tid] = c1b[tid];
    const float* src = bpp + (size_t)b * Tn * Tn;
    for (int i = tid; i < 68 * 18; i += 256) {
        const int r = i / 18, cq = i % 18;
        const int gy = y0 - 2 + r, gx = x0 - 4 + cq * 4;
        float4 v = make_float4(0.f, 0.f, 0.f, 0.f);
        if (gy >= 0 && gy < Tn && gx >= 0 && gx < Tn)
            v = *(const float4*)(src + (size_t)gy * Tn + gx);
        *(float4*)&inb[r][cq * 4] = v;
    }
    __syncthreads();

    float acc[4][4] = {};
    for (int ch = 0; ch < 16; ++ch) {
        if (ch) __syncthreads();   // prev conv2 reads done before h1 overwrite
        float w1r[9], w2r[9];
#pragma unroll
        for (int k = 0; k < 9; ++k) { w1r[k] = w1s[ch][k]; w2r[k] = w2s[ch][k]; }
        const float b1v = b1s[ch];
        // conv1: h1 positions 66 rows x 17 quads (68 cols, 2 spare)
        for (int i = tid; i < 66 * 17; i += 256) {
            const int rr = i / 17, q = i % 17;
            float v[3][8];
#pragma unroll
            for (int dy = 0; dy < 3; ++dy) {
                float4 p0 = *(const float4*)&inb[rr + dy][q * 4];
                float4 p1 = *(const float4*)&inb[rr + dy][q * 4 + 4];
                v[dy][0] = p0.x; v[dy][1] = p0.y; v[dy][2] = p0.z; v[dy][3] = p0.w;
                v[dy][4] = p1.x; v[dy][5] = p1.y; v[dy][6] = p1.z; v[dy][7] = p1.w;
            }
            const int gy = y0 + rr - 1;
            const int gxb = x0 + q * 4 - 1;
            const bool rowok = (gy >= 0 && gy < Tn);
            float o4[4];
#pragma unroll
            for (int j = 0; j < 3 + 1; ++j) {
                float s = b1v;
#pragma unroll
                for (int dy = 0; dy < 3; ++dy)
#pragma unroll
                    for (int dx = 0; dx < 3; ++dx)
                        s += v[dy][2 + j + dx] * w1r[dy * 3 + dx];
                const int gx = gxb + j;
                o4[j] = (rowok && gx >= 0 && gx < Tn) ? fmaxf(s, 0.0f) : 0.0f;
            }
            *(float4*)&h1[rr][q * 4] = make_float4(o4[0], o4[1], o4[2], o4[3]);
        }
        __syncthreads();
        // conv2: 4x4 outputs per thread from 6x6 h1 window
        float h[6][6];
#pragma unroll
        for (int r6 = 0; r6 < 6; ++r6) {
            float4 a = *(const float4*)&h1[ty * 4 + r6][tx * 4];
            float2 b2 = *(const float2*)&h1[ty * 4 + r6][tx * 4 + 4];
            h[r6][0] = a.x; h[r6][1] = a.y; h[r6][2] = a.z; h[r6][3] = a.w;
            h[r6][4] = b2.x; h[r6][5] = b2.y;
        }
#pragma unroll
        for (int i2 = 0; i2 < 4; ++i2)
#pragma unroll
            for (int j = 0; j < 4; ++j) {
                float s = 0.0f;
#pragma unroll
                for (int dy = 0; dy < 3; ++dy)
#pragma unroll
                    for (int dx = 0; dx < 3; ++dx)
                        s += h[i2 + dy][j + dx] * w2r[dy * 3 + dx];
                acc[i2][j] += s;
            }
    }
    const float ob = c2b[0];
#pragma unroll
    for (int i2 = 0; i2 < 4; ++i2) {
        float4 o = make_float4(acc[i2][0] + ob, acc[i2][1] + ob,
                               acc[i2][2] + ob, acc[i2][3] + ob);
        *(float4*)(biasout + ((size_t)b * Tn + y0 + ty * 4 + i2) * Tn + x0 + tx * 4) = o;
    }
}

// ---------------------------------------------------------------------------
// Split-bf16 MFMA GEMM: out = A @ W^T (+bias). A:[M,512] f32 (split on the
// fly). W pre-split planes. 128x128 tile, BK=64, 4 waves, reg-prefetch.
// mode 0: f32 [M,512]; mode 1: f32 scatter [b,h,t,d];
// mode 2: bf16 hi/lo planes [b,h,t,d]; mode 3: bf16 hi/lo planes [b,h,d,t].
// ---------------------------------------------------------------------------
__global__ __launch_bounds__(256) void gemm_mfma_kernel(
    const float* __restrict__ A,
    const unsigned short* __restrict__ Wh, const unsigned short* __restrict__ Wl,
    const float* __restrict__ bias, float* __restrict__ outf,
    unsigned short* __restrict__ out_hi, unsigned short* __restrict__ out_lo,
    int M, int L, int mode) {
    constexpr int K = 512, BK = 64, LDT = 72;
    __shared__ __align__(16) unsigned short AhT[128 * LDT];
    __shared__ __align__(16) unsigned short AlT[128 * LDT];
    __shared__ __align__(16) unsigned short WhT[128 * LDT];
    __shared__ __align__(16) unsigned short WlT[128 * LDT];
    const int tid = threadIdx.x;
    const int nbase = blockIdx.x * 128, mbase = blockIdx.y * 128;
    const int wave = tid >> 6, lane = tid & 63;
    const int wr = wave >> 1, wc = wave & 1;
    const int lg = lane >> 4, lr = lane & 15;
    f32x4 acc[4][4] = {};

    float4 pa0[4], pa1[4];
    s16x8 pwh[4], pwl[4];
    auto issue_loads = [&](int k0) {
#pragma unroll
        for (int c = 0; c < 4; ++c) {
            const int g = tid + 256 * c;
            const int row = g >> 3, col8 = (g & 7) * 8;
            int gm = mbase + row; if (gm >= M) gm = M - 1;
            const float* ap = A + (size_t)gm * K + k0 + col8;
            pa0[c] = *(const float4*)ap;
            pa1[c] = *(const float4*)(ap + 4);
            const size_t gw = (size_t)(nbase + row) * K + k0 + col8;
            pwh[c] = *(const s16x8*)&Wh[gw];
            pwl[c] = *(const s16x8*)&Wl[gw];
        }
    };
    issue_loads(0);
    for (int ks = 0; ks < K / BK; ++ks) {
        __syncthreads();   // frag reads of previous step complete
#pragma unroll
        for (int c = 0; c < 4; ++c) {
            const int g = tid + 256 * c;
            const int row = g >> 3, col8 = (g & 7) * 8;
            float av[8] = {pa0[c].x, pa0[c].y, pa0[c].z, pa0[c].w,
                           pa1[c].x, pa1[c].y, pa1[c].z, pa1[c].w};
            s16x8 hh, ll;
#pragma unroll
            for (int j = 0; j < 8; ++j) {
                unsigned short x = f2bf(av[j]);
                hh[j] = (short)x;
                ll[j] = (short)f2bf(av[j] - bf2f(x));
            }
            const int loff = row * LDT + col8;
            *(s16x8*)&AhT[loff] = hh;
            *(s16x8*)&AlT[loff] = ll;
            *(s16x8*)&WhT[loff] = pwh[c];
            *(s16x8*)&WlT[loff] = pwl[c];
        }
        if (ks < K / BK - 1) issue_loads((ks + 1) * BK);
        __syncthreads();
#pragma unroll
        for (int kk = 0; kk < 2; ++kk) {
            s16x8 wh[4], wl[4];
#pragma unroll
            for (int nj = 0; nj < 4; ++nj) {
                const int off = (wc * 64 + nj * 16 + lr) * LDT + kk * 32 + lg * 8;
                wh[nj] = *(const s16x8*)&WhT[off];
                wl[nj] = *(const s16x8*)&WlT[off];
            }
#pragma unroll
            for (int mi = 0; mi < 4; ++mi) {
                const int off = (wr * 64 + mi * 16 + lr) * LDT + kk * 32 + lg * 8;
                s16x8 ah = *(const s16x8*)&AhT[off];
                s16x8 al = *(const s16x8*)&AlT[off];
#pragma unroll
                for (int nj = 0; nj < 4; ++nj)
                    acc[mi][nj] = __builtin_amdgcn_mfma_f32_16x16x32_bf16(ah, wh[nj], acc[mi][nj], 0, 0, 0);
#pragma unroll
                for (int nj = 0; nj < 4; ++nj)
                    acc[mi][nj] = __builtin_amdgcn_mfma_f32_16x16x32_bf16(ah, wl[nj], acc[mi][nj], 0, 0, 0);
#pragma unroll
                for (int nj = 0; nj < 4; ++nj)
                    acc[mi][nj] = __builtin_amdgcn_mfma_f32_16x16x32_bf16(al, wh[nj], acc[mi][nj], 0, 0, 0);
            }
        }
    }
#pragma unroll
    for (int nj = 0; nj < 4; ++nj) {
        const int n = nbase + wc * 64 + nj * 16 + lr;
        const float bv = bias ? bias[n] : 0.0f;
#pragma unroll
        for (int mi = 0; mi < 4; ++mi) {
#pragma unroll
            for (int r2 = 0; r2 < 4; ++r2) {
                const int m = mbase + wr * 64 + mi * 16 + lg * 4 + r2;
                if (m < M) {
                    const float v = acc[mi][nj][r2] + bv;
                    if (mode == 0) {
                        outf[(size_t)m * 512 + n] = v;
                    } else if (mode == 1) {
                        int bb = m / L, t = m - bb * L;
                        int hh2 = n >> 5, d = n & 31;
                        outf[(((size_t)bb * Hn + hh2) * L + t) * DHn + d] = v;
                    } else {
                        int bb = m / L, t = m - bb * L;
                        int hh2 = n >> 5, d = n & 31;
                        size_t oidx = (mode == 2)
                            ? ((((size_t)bb * Hn + hh2) * L + t) * DHn + d)
                            : ((((size_t)bb * Hn + hh2) * DHn + d) * L + t);
                        unsigned short hi16 = f2bf(v);
                        out_hi[oidx] = hi16;
                        out_lo[oidx] = f2bf(v - bf2f(hi16));
                    }
                }
            }
        }
    }
}

// ---------------------------------------------------------------------------
// MFMA fused attention. Grid (T/32, H, B), 256 threads = 4 waves.
// ---------------------------------------------------------------------------
__global__ __launch_bounds__(256, 2) void attn_mfma_kernel(
    const float* __restrict__ q_ws,
    const unsigned short* __restrict__ k_hi, const unsigned short* __restrict__ k_lo,
    const unsigned short* __restrict__ vt_hi, const unsigned short* __restrict__ vt_lo,
    const unsigned short* __restrict__ p_hi, const unsigned short* __restrict__ p_lo,
    const float* __restrict__ biasw, const float* __restrict__ maskw,
    const float* __restrict__ ub, const float* __restrict__ vb,
    float* __restrict__ ctx) {
    const int t0 = blockIdx.x * 32, h = blockIdx.y, b = blockIdx.z;
    const int tid = threadIdx.x;
    const int w = tid >> 6, l = tid & 63;
    const int lr = l & 15, lg = l >> 4;
    const size_t bh = (size_t)b * Hn + h;
    const int pbase = 480 - t0;
    const float scale = 0.17677669529663687f;  // 1/sqrt(32)

    __shared__ unsigned short attn_hi_l[4][32 * 64];
    __shared__ unsigned short attn_lo_l[4][32 * 64];
    __shared__ float ctxred[4][32][36];
    __shared__ float redbuf[2][32][4];

    s16x8 quh[2], qul[2], qvh[2], qvl[2];
#pragma unroll
    for (int i = 0; i < 2; ++i) {
        const float* qrow = q_ws + (bh * Tn + t0 + 16 * i + lr) * DHn + lg * 8;
        float4 qa = *(const float4*)qrow;
        float4 qb = *(const float4*)(qrow + 4);
        float qv8[8] = {qa.x, qa.y, qa.z, qa.w, qb.x, qb.y, qb.z, qb.w};
#pragma unroll
        for (int j = 0; j < 8; ++j) {
            const float uj = ub[h * DHn + lg * 8 + j];
            const float vj = vb[h * DHn + lg * 8 + j];
            float xu = qv8[j] + uj;
            unsigned short hu = f2bf(xu);
            quh[i][j] = (short)hu; qul[i][j] = (short)f2bf(xu - bf2f(hu));
            float xv = qv8[j] + vj;
            unsigned short hv = f2bf(xv);
            qvh[i][j] = (short)hv; qvl[i][j] = (short)f2bf(xv - bf2f(hv));
        }
    }
    float mv[8];
#pragma unroll
    for (int m = 0; m < 8; ++m)
        mv[m] = maskw[b * Tn + w * 128 + m * 16 + lr];

    auto posTile = [&](int i, int jt) -> f32x4 {
        int pidx = pbase + w * 128 + jt * 16 + lr;
        if (pidx > Pn - 1) pidx = Pn - 1;
        const size_t po = (bh * Pn + pidx) * DHn + lg * 8;
        s16x8 ph = *(const s16x8*)(p_hi + po);
        s16x8 pl = *(const s16x8*)(p_lo + po);
        f32x4 t = {0.f, 0.f, 0.f, 0.f};
        return mfma3(qvh[i], qvl[i], ph, pl, t);
    };

    f32x4 sc[2][8];
    f32x4 p0a = posTile(0, 1);
    f32x4 p1a = posTile(1, 0);
    const int ubase = lr - 4 * lg + 31;

#pragma unroll
    for (int m = 0; m < 8; ++m) {
        f32x4 p0b = posTile(0, m + 2);
        f32x4 p1b = posTile(1, m + 1);
        float bvls[2][4];
#pragma unroll
        for (int i2 = 0; i2 < 2; ++i2)
#pragma unroll
            for (int r2 = 0; r2 < 4; ++r2)
                bvls[i2][r2] = biasw[((size_t)b * Tn + t0 + 16 * i2 + 4 * lg + r2) * Tn
                                     + w * 128 + m * 16 + lr];
        const size_t ko = (bh * Tn + w * 128 + m * 16 + lr) * DHn + lg * 8;
        s16x8 kh = *(const s16x8*)(k_hi + ko);
        s16x8 kl = *(const s16x8*)(k_lo + ko);
#pragma unroll
        for (int i = 0; i < 2; ++i) {
            f32x4 c = {0.f, 0.f, 0.f, 0.f};
            c = mfma3(quh[i], qul[i], kh, kl, c);
            f32x4 Pa = (i == 0) ? p0a : p1a;
            f32x4 Pb = (i == 0) ? p0b : p1b;
            f32x4 out;
#pragma unroll
            for (int r2 = 0; r2 < 4; ++r2) {
                const int u = ubase - r2;
                const int src = (l & 48) | (u & 15);
                float pa = __shfl(Pa[r2], src, 64);
                float pb = __shfl(Pb[r2], src, 64);
                float pv = (u < 32) ? pa : pb;
                float v = (c[r2] + pv) * scale + bvls[i][r2];
                if (mv[m] != 0.0f) v = -10000.0f;
                out[r2] = v;
            }
            sc[i][m] = out;
        }
        p0a = p0b; p1a = p1b;
    }

    float rowm[2][4], inv[2][4];
#pragma unroll
    for (int i = 0; i < 2; ++i)
#pragma unroll
        for (int r2 = 0; r2 < 4; ++r2) {
            float mx = -1e30f;
#pragma unroll
            for (int m = 0; m < 8; ++m) mx = fmaxf(mx, sc[i][m][r2]);
#pragma unroll
            for (int off = 1; off < 16; off <<= 1) mx = fmaxf(mx, __shfl_xor(mx, off, 64));
            if (lr == 0) redbuf[0][16 * i + 4 * lg + r2][w] = mx;
        }
    __syncthreads();
#pragma unroll
    for (int i = 0; i < 2; ++i)
#pragma unroll
        for (int r2 = 0; r2 < 4; ++r2) {
            float4 mm = *(const float4*)redbuf[0][16 * i + 4 * lg + r2];
            rowm[i][r2] = fmaxf(fmaxf(mm.x, mm.y), fmaxf(mm.z, mm.w));
        }
    float psum[2][4] = {};
#pragma unroll
    for (int i = 0; i < 2; ++i)
#pragma unroll
        for (int m = 0; m < 8; ++m)
#pragma unroll
            for (int r2 = 0; r2 < 4; ++r2) {
                float e = __expf(sc[i][m][r2] - rowm[i][r2]);
                sc[i][m][r2] = e;
                psum[i][r2] += e;
            }
#pragma unroll
    for (int i = 0; i < 2; ++i)
#pragma unroll
        for (int r2 = 0; r2 < 4; ++r2) {
            float s = psum[i][r2];
#pragma unroll
            for (int off = 1; off < 16; off <<= 1) s += __shfl_xor(s, off, 64);
            if (lr == 0) redbuf[1][16 * i + 4 * lg + r2][w] = s;
        }
    __syncthreads();
#pragma unroll
    for (int i = 0; i < 2; ++i)
#pragma unroll
        for (int r2 = 0; r2 < 4; ++r2) {
            float4 ss = *(const float4*)redbuf[1][16 * i + 4 * lg + r2];
            inv[i][r2] = 1.0f / (ss.x + ss.y + ss.z + ss.w);
        }

    f32x4 cacc[2][2] = {};
#pragma unroll
    for (int sh = 0; sh < 2; ++sh) {
        __syncthreads();
#pragma unroll
        for (int mm2 = 0; mm2 < 4; ++mm2) {
            const int m = sh * 4 + mm2;
#pragma unroll
            for (int i = 0; i < 2; ++i)
#pragma unroll
                for (int r2 = 0; r2 < 4; ++r2) {
                    const int trow = 16 * i + 4 * lg + r2;
                    float a = sc[i][m][r2] * inv[i][r2];
                    unsigned short ah16 = f2bf(a);
                    unsigned short al16 = f2bf(a - bf2f(ah16));
                    const int cbyte = (mm2 * 16 + lr) * 2;
                    const int off = trow * 128 + (cbyte ^ ((trow & 7) << 4));
                    *(unsigned short*)((char*)attn_hi_l[w] + off) = ah16;
                    *(unsigned short*)((char*)attn_lo_l[w] + off) = al16;
                }
        }
        __syncthreads();
#pragma unroll
        for (int ks = 0; ks < 2; ++ks) {
            s16x8 pah[2], pal[2];
#pragma unroll
            for (int i = 0; i < 2; ++i) {
                const int trow = 16 * i + lr;
                const int cbyte = ks * 64 + lg * 16;
                const int off = trow * 128 + (cbyte ^ ((trow & 7) << 4));
                pah[i] = *(const s16x8*)((char*)attn_hi_l[w] + off);
                pal[i] = *(const s16x8*)((char*)attn_lo_l[w] + off);
            }
#pragma unroll
            for (int n = 0; n < 2; ++n) {
                const int sg = w * 128 + sh * 64 + ks * 32 + lg * 8;
                const size_t vo = (bh * DHn + n * 16 + lr) * Tn + sg;
                s16x8 vh = *(const s16x8*)(vt_hi + vo);
                s16x8 vl = *(const s16x8*)(vt_lo + vo);
#pragma unroll
                for (int i = 0; i < 2; ++i)
                    cacc[i][n] = mfma3(pah[i], pal[i], vh, vl, cacc[i][n]);
            }
        }
    }

#pragma unroll
    for (int i = 0; i < 2; ++i)
#pragma unroll
        for (int n = 0; n < 2; ++n)
#pragma unroll
            for (int r2 = 0; r2 < 4; ++r2)
                ctxred[w][16 * i + 4 * lg + r2][n * 16 + lr] = cacc[i][n][r2];
    __syncthreads();
    {
        const int trow = tid >> 3, d0 = (tid & 7) * 4;
        float4 s0 = *(const float4*)&ctxred[0][trow][d0];
        float4 s1 = *(const float4*)&ctxred[1][trow][d0];
        float4 s2 = *(const float4*)&ctxred[2][trow][d0];
        float4 s3 = *(const float4*)&ctxred[3][trow][d0];
        float4 o = make_float4(s0.x + s1.x + s2.x + s3.x, s0.y + s1.y + s2.y + s3.y,
                               s0.z + s1.z + s2.z + s3.z, s0.w + s1.w + s2.w + s3.w);
        *(float4*)(ctx + ((size_t)b * Tn + t0 + trow) * Dn + h * DHn + d0) = o;
    }
}

// ---------------------------------------------------------------------------
extern "C" void kernel_launch(void* const* d_in, const int* in_sizes, int n_in,
                              void* d_out, int out_size, void* d_ws, size_t ws_size,
                              hipStream_t stream) {
    const float* query = (const float*)d_in[0];
    const float* key   = (const float*)d_in[1];
    const float* value = (const float*)d_in[2];
    const float* pos   = (const float*)d_in[3];
    const unsigned char* mask = (const unsigned char*)d_in[4];
    const float* bpp = (const float*)d_in[5];
    const float* Wq = (const float*)d_in[6];
    const float* bq = (const float*)d_in[7];
    const float* Wk = (const float*)d_in[8];
    const float* bk = (const float*)d_in[9];
    const float* Wv = (const float*)d_in[10];
    const float* bv = (const float*)d_in[11];
    const float* Wp = (const float*)d_in[12];
    const float* Wo = (const float*)d_in[13];
    const float* bo = (const float*)d_in[14];
    const float* ub = (const float*)d_in[15];
    const float* vbias = (const float*)d_in[16];
    const float* c1w = (const float*)d_in[17];
    const float* c1b = (const float*)d_in[18];
    const float* c2w = (const float*)d_in[19];
    const float* c2b = (const float*)d_in[20];

    const size_t qkvE = (size_t)Bn * Hn * Tn * DHn;   // 4.19M
    const size_t posE = (size_t)Bn * Hn * Pn * DHn;   // 8.38M
    const size_t wE   = (size_t)Dn * Dn;

    float* ws = (float*)d_ws;
    float* bias_ws = ws;                                // [B,T,T]
    float* mask_ws = bias_ws + (size_t)Bn * Tn * Tn;    // [B,T]
    float* q_ws    = mask_ws + Bn * Tn;                 // [B,H,T,DH] f32
    float* ctx_ws  = q_ws + qkvE;                       // [B,T,D] f32
    unsigned short* k_hi = (unsigned short*)(ctx_ws + (size_t)Bn * Tn * Dn);
    unsigned short* k_lo = k_hi + qkvE;
    unsigned short* v_hi = k_lo + qkvE;                 // transposed [B,H,DH,T]
    unsigned short* v_lo = v_hi + qkvE;
    unsigned short* p_hi = v_lo + qkvE;                 // [B,H,P,DH]
    unsigned short* p_lo = p_hi + posE;
    unsigned short* wall_hi = p_lo + posE;              // 5 x [D,D]
    unsigned short* wall_lo = wall_hi + 5 * wE;

    // weight order: 0=Wq 1=Wk 2=Wv 3=Wp 4=Wo
    split_weights_kernel<<<dim3(64, 5), dim3(256), 0, stream>>>(
        Wq, Wk, Wv, Wp, Wo, wall_hi, wall_lo);
    mask_decode_kernel<<<dim3(1), dim3(256), 0, stream>>>(mask, mask_ws);
    conv_bias_kernel<<<dim3(8, 8, Bn), dim3(256), 0, stream>>>(
        bpp, c1w, c1b, c2w, c2b, bias_ws);

    gemm_mfma_kernel<<<dim3(4, 64), dim3(256), 0, stream>>>(
        query, wall_hi + 0 * wE, wall_lo + 0 * wE, bq, q_ws, nullptr, nullptr,
        Bn * Tn, Tn, 1);
    gemm_mfma_kernel<<<dim3(4, 64), dim3(256), 0, stream>>>(
        key, wall_hi + 1 * wE, wall_lo + 1 * wE, bk, nullptr, k_hi, k_lo,
        Bn * Tn, Tn, 2);
    gemm_mfma_kernel<<<dim3(4, 64), dim3(256), 0, stream>>>(
        value, wall_hi + 2 * wE, wall_lo + 2 * wE, bv, nullptr, v_hi, v_lo,
        Bn * Tn, Tn, 3);
    gemm_mfma_kernel<<<dim3(4, 128), dim3(256), 0, stream>>>(
        pos, wall_hi + 3 * wE, wall_lo + 3 * wE, nullptr, nullptr, p_hi, p_lo,
        Bn * Pn, Pn, 2);

    attn_mfma_kernel<<<dim3(Tn / 32, Hn, Bn), dim3(256), 0, stream>>>(
        q_ws, k_hi, k_lo, v_hi, v_lo, p_hi, p_lo, bias_ws, mask_ws, ub, vbias, ctx_ws);

    gemm_mfma_kernel<<<dim3(4, 64), dim3(256), 0, stream>>>(
        ctx_ws, wall_hi + 4 * wE, wall_lo + 4 * wE, bo, (float*)d_out, nullptr, nullptr,
        Bn * Tn, Tn, 0);
}

// Round 5
// 475.317 us; speedup vs baseline: 2.3624x; 1.0942x over previous
//
#include <hip/hip_runtime.h>

constexpr int Bn  = 16;
constexpr int Tn  = 512;
constexpr int Dn  = 512;
constexpr int Hn  = 16;
constexpr int DHn = 32;
constexpr int Pn  = 1023;   // 2T-1
constexpr size_t wE = (size_t)Dn * Dn;

typedef __attribute__((ext_vector_type(8))) short s16x8;
typedef __attribute__((ext_vector_type(4))) float f32x4;
typedef unsigned short ushort_t;

__device__ __forceinline__ unsigned short f2bf(float x) {
    unsigned u = __float_as_uint(x);
    unsigned r = u + 0x7fff + ((u >> 16) & 1);
    return (unsigned short)(r >> 16);
}
__device__ __forceinline__ float bf2f(unsigned short h) {
    return __uint_as_float(((unsigned)h) << 16);
}

__device__ __forceinline__ f32x4 mfma3(s16x8 ah, s16x8 al, s16x8 bh2, s16x8 bl, f32x4 c) {
    c = __builtin_amdgcn_mfma_f32_16x16x32_bf16(ah, bh2, c, 0, 0, 0);
    c = __builtin_amdgcn_mfma_f32_16x16x32_bf16(ah, bl,  c, 0, 0, 0);
    c = __builtin_amdgcn_mfma_f32_16x16x32_bf16(al, bh2, c, 0, 0, 0);
    return c;
}

// ---------------------------------------------------------------------------
// Split all 5 weight matrices (512x512 each) in one dispatch. grid (64, 5).
// ---------------------------------------------------------------------------
__global__ __launch_bounds__(256) void split_weights_kernel(
    const float* __restrict__ w0, const float* __restrict__ w1,
    const float* __restrict__ w2, const float* __restrict__ w3,
    const float* __restrict__ w4,
    unsigned short* __restrict__ hi, unsigned short* __restrict__ lo) {
    const float* srcs[5] = {w0, w1, w2, w3, w4};
    const float* src = srcs[blockIdx.y];
    const size_t off = (size_t)blockIdx.y * wE;
    unsigned short* h = hi + off;
    unsigned short* l = lo + off;
    const int n4 = Dn * Dn / 4;
    for (int i = blockIdx.x * 256 + threadIdx.x; i < n4; i += 64 * 256) {
        float4 v = ((const float4*)src)[i];
        ushort4 hh, ll;
        hh.x = f2bf(v.x); ll.x = f2bf(v.x - bf2f(hh.x));
        hh.y = f2bf(v.y); ll.y = f2bf(v.y - bf2f(hh.y));
        hh.z = f2bf(v.z); ll.z = f2bf(v.z - bf2f(hh.z));
        hh.w = f2bf(v.w); ll.w = f2bf(v.w - bf2f(hh.w));
        ((ushort4*)h)[i] = hh;
        ((ushort4*)l)[i] = ll;
    }
}

// ---------------------------------------------------------------------------
// Mask decode: detect layout (int32 / byte-bool / float32) then write 0/1 flags
// ---------------------------------------------------------------------------
__global__ void mask_decode_kernel(const unsigned char* __restrict__ mraw,
                                   float* __restrict__ mout) {
    __shared__ int s_nonmod4;
    __shared__ int s_big;
    if (threadIdx.x == 0) { s_nonmod4 = 0; s_big = 0; }
    __syncthreads();
    int f0 = 0, f1 = 0;
    for (int i = threadIdx.x; i < Bn * Tn; i += 256) {
        unsigned char v = mraw[i];
        if ((i & 3) != 0 && v != 0) f0 = 1;
        if (v > 1) f1 = 1;
    }
    if (f0) atomicOr(&s_nonmod4, 1);
    if (f1) atomicOr(&s_big, 1);
    __syncthreads();
    const int layout = s_big ? 2 : (s_nonmod4 ? 1 : 0);
    for (int i = threadIdx.x; i < Bn * Tn; i += 256) {
        bool m;
        if (layout == 2)      m = ((const float*)mraw)[i] != 0.0f;
        else if (layout == 1) m = mraw[i] != 0;
        else                  m = ((const int*)mraw)[i] != 0;
        mout[i] = m ? 1.0f : 0.0f;
    }
}

// ---------------------------------------------------------------------------
// Fused conv bias -> bf16 output. 64x64 tile per block, 4x4 per thread.
// ---------------------------------------------------------------------------
__global__ __launch_bounds__(256) void conv_bias_kernel(
    const float* __restrict__ bpp, const float* __restrict__ c1w,
    const float* __restrict__ c1b, const float* __restrict__ c2w,
    const float* __restrict__ c2b, unsigned short* __restrict__ biasout) {
    const int x0 = blockIdx.x * 64, y0 = blockIdx.y * 64, b = blockIdx.z;
    __shared__ __align__(16) float inb[68][72];
    __shared__ __align__(16) float h1[66][72];
    __shared__ float w1s[16][9], w2s[16][9], b1s[16];
    const int tid = threadIdx.x;
    const int tx = tid & 15, ty = tid >> 4;

    if (tid < 144) { w1s[tid / 9][tid % 9] = c1w[tid]; w2s[tid / 9][tid % 9] = c2w[tid]; }
    if (tid < 16) b1s[tid] = c1b[tid];
    const float* src = bpp + (size_t)b * Tn * Tn;
    for (int i = tid; i < 68 * 18; i += 256) {
        const int r = i / 18, cq = i % 18;
        const int gy = y0 - 2 + r, gx = x0 - 4 + cq * 4;
        float4 v = make_float4(0.f, 0.f, 0.f, 0.f);
        if (gy >= 0 && gy < Tn && gx >= 0 && gx < Tn)
            v = *(const float4*)(src + (size_t)gy * Tn + gx);
        *(float4*)&inb[r][cq * 4] = v;
    }
    __syncthreads();

    float acc[4][4] = {};
    for (int ch = 0; ch < 16; ++ch) {
        if (ch) __syncthreads();
        float w1r[9], w2r[9];
#pragma unroll
        for (int k = 0; k < 9; ++k) { w1r[k] = w1s[ch][k]; w2r[k] = w2s[ch][k]; }
        const float b1v = b1s[ch];
        for (int i = tid; i < 66 * 17; i += 256) {
            const int rr = i / 17, q = i % 17;
            float v[3][8];
#pragma unroll
            for (int dy = 0; dy < 3; ++dy) {
                float4 p0 = *(const float4*)&inb[rr + dy][q * 4];
                float4 p1 = *(const float4*)&inb[rr + dy][q * 4 + 4];
                v[dy][0] = p0.x; v[dy][1] = p0.y; v[dy][2] = p0.z; v[dy][3] = p0.w;
                v[dy][4] = p1.x; v[dy][5] = p1.y; v[dy][6] = p1.z; v[dy][7] = p1.w;
            }
            const int gy = y0 + rr - 1;
            const int gxb = x0 + q * 4 - 1;
            const bool rowok = (gy >= 0 && gy < Tn);
            float o4[4];
#pragma unroll
            for (int j = 0; j < 4; ++j) {
                float s = b1v;
#pragma unroll
                for (int dy = 0; dy < 3; ++dy)
#pragma unroll
                    for (int dx = 0; dx < 3; ++dx)
                        s += v[dy][2 + j + dx] * w1r[dy * 3 + dx];
                const int gx = gxb + j;
                o4[j] = (rowok && gx >= 0 && gx < Tn) ? fmaxf(s, 0.0f) : 0.0f;
            }
            *(float4*)&h1[rr][q * 4] = make_float4(o4[0], o4[1], o4[2], o4[3]);
        }
        __syncthreads();
        float h[6][6];
#pragma unroll
        for (int r6 = 0; r6 < 6; ++r6) {
            float4 a = *(const float4*)&h1[ty * 4 + r6][tx * 4];
            float2 b2 = *(const float2*)&h1[ty * 4 + r6][tx * 4 + 4];
            h[r6][0] = a.x; h[r6][1] = a.y; h[r6][2] = a.z; h[r6][3] = a.w;
            h[r6][4] = b2.x; h[r6][5] = b2.y;
        }
#pragma unroll
        for (int i2 = 0; i2 < 4; ++i2)
#pragma unroll
            for (int j = 0; j < 4; ++j) {
                float s = 0.0f;
#pragma unroll
                for (int dy = 0; dy < 3; ++dy)
#pragma unroll
                    for (int dx = 0; dx < 3; ++dx)
                        s += h[i2 + dy][j + dx] * w2r[dy * 3 + dx];
                acc[i2][j] += s;
            }
    }
    const float ob = c2b[0];
#pragma unroll
    for (int i2 = 0; i2 < 4; ++i2) {
        ushort4 o;
        o.x = f2bf(acc[i2][0] + ob); o.y = f2bf(acc[i2][1] + ob);
        o.z = f2bf(acc[i2][2] + ob); o.w = f2bf(acc[i2][3] + ob);
        *(ushort4*)(biasout + ((size_t)b * Tn + y0 + ty * 4 + i2) * Tn + x0 + tx * 4) = o;
    }
}

// ---------------------------------------------------------------------------
// Split-bf16 MFMA GEMM body. out = A @ W^T (+bias). A:[M,512] f32 (split on
// the fly). W pre-split planes. Tile 128 x NT, BK=64, 4 waves, reg-prefetch.
// mode 0: f32 [M,512]; mode 1: f32 scatter [b,h,t,d];
// mode 2: bf16 planes [b,h,t,d]; mode 3: bf16 planes [b,h,d,t].
// ---------------------------------------------------------------------------
template<int NT>
__device__ __forceinline__ void gemm_body(
    const float* __restrict__ A,
    const unsigned short* __restrict__ Wh, const unsigned short* __restrict__ Wl,
    const float* __restrict__ bias, float* __restrict__ outf,
    unsigned short* __restrict__ out_hi, unsigned short* __restrict__ out_lo,
    int M, int L, int mode, int nbase, int mbase) {
    constexpr int K = 512, BK = 64, LDT = 72, NW = NT / 32;
    __shared__ __align__(16) unsigned short AhT[128 * LDT];
    __shared__ __align__(16) unsigned short AlT[128 * LDT];
    __shared__ __align__(16) unsigned short WhT[NT * LDT];
    __shared__ __align__(16) unsigned short WlT[NT * LDT];
    const int tid = threadIdx.x;
    const int wave = tid >> 6, lane = tid & 63;
    const int wr = wave >> 1, wc = wave & 1;
    const int lg = lane >> 4, lr = lane & 15;
    f32x4 acc[4][NW] = {};

    float4 pa0[4], pa1[4];
    s16x8 pwh[NW], pwl[NW];
    auto issue_loads = [&](int k0) {
#pragma unroll
        for (int c = 0; c < 4; ++c) {
            const int g = tid + 256 * c;
            const int row = g >> 3, col8 = (g & 7) * 8;
            int gm = mbase + row; if (gm >= M) gm = M - 1;
            const float* ap = A + (size_t)gm * K + k0 + col8;
            pa0[c] = *(const float4*)ap;
            pa1[c] = *(const float4*)(ap + 4);
        }
#pragma unroll
        for (int c = 0; c < NW; ++c) {
            const int g = tid + 256 * c;
            const int row = g >> 3, col8 = (g & 7) * 8;
            const size_t gw = (size_t)(nbase + row) * K + k0 + col8;
            pwh[c] = *(const s16x8*)&Wh[gw];
            pwl[c] = *(const s16x8*)&Wl[gw];
        }
    };
    issue_loads(0);
    for (int ks = 0; ks < K / BK; ++ks) {
        __syncthreads();
#pragma unroll
        for (int c = 0; c < 4; ++c) {
            const int g = tid + 256 * c;
            const int row = g >> 3, col8 = (g & 7) * 8;
            float av[8] = {pa0[c].x, pa0[c].y, pa0[c].z, pa0[c].w,
                           pa1[c].x, pa1[c].y, pa1[c].z, pa1[c].w};
            s16x8 hh, ll;
#pragma unroll
            for (int j = 0; j < 8; ++j) {
                unsigned short x = f2bf(av[j]);
                hh[j] = (short)x;
                ll[j] = (short)f2bf(av[j] - bf2f(x));
            }
            const int loff = row * LDT + col8;
            *(s16x8*)&AhT[loff] = hh;
            *(s16x8*)&AlT[loff] = ll;
        }
#pragma unroll
        for (int c = 0; c < NW; ++c) {
            const int g = tid + 256 * c;
            const int loff = (g >> 3) * LDT + (g & 7) * 8;
            *(s16x8*)&WhT[loff] = pwh[c];
            *(s16x8*)&WlT[loff] = pwl[c];
        }
        if (ks < K / BK - 1) issue_loads((ks + 1) * BK);
        __syncthreads();
#pragma unroll
        for (int kk = 0; kk < 2; ++kk) {
            s16x8 wh[NW], wl[NW];
#pragma unroll
            for (int nj = 0; nj < NW; ++nj) {
                const int off = (wc * (NT / 2) + nj * 16 + lr) * LDT + kk * 32 + lg * 8;
                wh[nj] = *(const s16x8*)&WhT[off];
                wl[nj] = *(const s16x8*)&WlT[off];
            }
#pragma unroll
            for (int mi = 0; mi < 4; ++mi) {
                const int off = (wr * 64 + mi * 16 + lr) * LDT + kk * 32 + lg * 8;
                s16x8 ah = *(const s16x8*)&AhT[off];
                s16x8 al = *(const s16x8*)&AlT[off];
#pragma unroll
                for (int nj = 0; nj < NW; ++nj)
                    acc[mi][nj] = __builtin_amdgcn_mfma_f32_16x16x32_bf16(ah, wh[nj], acc[mi][nj], 0, 0, 0);
#pragma unroll
                for (int nj = 0; nj < NW; ++nj)
                    acc[mi][nj] = __builtin_amdgcn_mfma_f32_16x16x32_bf16(ah, wl[nj], acc[mi][nj], 0, 0, 0);
#pragma unroll
                for (int nj = 0; nj < NW; ++nj)
                    acc[mi][nj] = __builtin_amdgcn_mfma_f32_16x16x32_bf16(al, wh[nj], acc[mi][nj], 0, 0, 0);
            }
        }
    }
#pragma unroll
    for (int nj = 0; nj < NW; ++nj) {
        const int n = nbase + wc * (NT / 2) + nj * 16 + lr;
        const float bv = bias ? bias[n] : 0.0f;
#pragma unroll
        for (int mi = 0; mi < 4; ++mi) {
#pragma unroll
            for (int r2 = 0; r2 < 4; ++r2) {
                const int m = mbase + wr * 64 + mi * 16 + lg * 4 + r2;
                if (m < M) {
                    const float v = acc[mi][nj][r2] + bv;
                    if (mode == 0) {
                        outf[(size_t)m * 512 + n] = v;
                    } else if (mode == 1) {
                        int bb = m / L, t = m - bb * L;
                        int hh2 = n >> 5, d = n & 31;
                        outf[(((size_t)bb * Hn + hh2) * L + t) * DHn + d] = v;
                    } else {
                        int bb = m / L, t = m - bb * L;
                        int hh2 = n >> 5, d = n & 31;
                        size_t oidx = (mode == 2)
                            ? ((((size_t)bb * Hn + hh2) * L + t) * DHn + d)
                            : ((((size_t)bb * Hn + hh2) * DHn + d) * L + t);
                        unsigned short hi16 = f2bf(v);
                        out_hi[oidx] = hi16;
                        out_lo[oidx] = f2bf(v - bf2f(hi16));
                    }
                }
            }
        }
    }
}

// Batched Q/K/V/P projections: grid (4, 128, 4); z = 0:Q 1:K 2:V 3:P.
__global__ __launch_bounds__(256) void gemm_qkvp_kernel(
    const float* __restrict__ q, const float* __restrict__ k,
    const float* __restrict__ v, const float* __restrict__ p,
    const unsigned short* __restrict__ wall_hi, const unsigned short* __restrict__ wall_lo,
    const float* __restrict__ bq, const float* __restrict__ bk,
    const float* __restrict__ bv,
    float* __restrict__ q_ws,
    unsigned short* __restrict__ k_hi, unsigned short* __restrict__ k_lo,
    unsigned short* __restrict__ v_hi, unsigned short* __restrict__ v_lo,
    unsigned short* __restrict__ p_hi, unsigned short* __restrict__ p_lo) {
    const int z = blockIdx.z;
    const float* A; const float* bias = nullptr;
    float* outf = nullptr; unsigned short *ohi = nullptr, *olo = nullptr;
    int M, L, mode;
    if (z == 0)      { A = q; bias = bq; outf = q_ws; M = Bn * Tn; L = Tn; mode = 1; }
    else if (z == 1) { A = k; bias = bk; ohi = k_hi; olo = k_lo; M = Bn * Tn; L = Tn; mode = 2; }
    else if (z == 2) { A = v; bias = bv; ohi = v_hi; olo = v_lo; M = Bn * Tn; L = Tn; mode = 3; }
    else             { A = p; ohi = p_hi; olo = p_lo; M = Bn * Pn; L = Pn; mode = 2; }
    const int mbase = blockIdx.y * 128;
    if (mbase >= M) return;
    gemm_body<128>(A, wall_hi + (size_t)z * wE, wall_lo + (size_t)z * wE, bias,
                   outf, ohi, olo, M, L, mode, blockIdx.x * 128, mbase);
}

// Output projection: grid (8, 64), 128x64 tiles.
__global__ __launch_bounds__(256) void gemm_o_kernel(
    const float* __restrict__ A,
    const unsigned short* __restrict__ Wh, const unsigned short* __restrict__ Wl,
    const float* __restrict__ bias, float* __restrict__ out) {
    gemm_body<64>(A, Wh, Wl, bias, out, nullptr, nullptr,
                  Bn * Tn, Tn, 0, blockIdx.x * 64, blockIdx.y * 128);
}

// ---------------------------------------------------------------------------
// MFMA fused attention. 1D grid 4096 with XCD-chunked swizzle. 4 waves.
// ---------------------------------------------------------------------------
__global__ __launch_bounds__(256, 2) void attn_mfma_kernel(
    const float* __restrict__ q_ws,
    const unsigned short* __restrict__ k_hi, const unsigned short* __restrict__ k_lo,
    const unsigned short* __restrict__ vt_hi, const unsigned short* __restrict__ vt_lo,
    const unsigned short* __restrict__ p_hi, const unsigned short* __restrict__ p_lo,
    const unsigned short* __restrict__ biasw, const float* __restrict__ maskw,
    const float* __restrict__ ub, const float* __restrict__ vb,
    float* __restrict__ ctx) {
    // swizzle: XCD (bid&7) owns contiguous 512-wg chunk = 2 b's; t0 fastest.
    const int bid = blockIdx.x;
    const int wg = ((bid & 7) << 9) | (bid >> 3);
    const int t0 = (wg & 15) * 32;
    const int h = (wg >> 4) & 15;
    const int b = wg >> 8;
    const int tid = threadIdx.x;
    const int w = tid >> 6, l = tid & 63;
    const int lr = l & 15, lg = l >> 4;
    const size_t bh = (size_t)b * Hn + h;
    const int pbase = 480 - t0;
    const float scale = 0.17677669529663687f;  // 1/sqrt(32)

    // per-wave union: [0,4096) attn_hi, [4096,8192) attn_lo; ctxred reuses [0,4608)
    __shared__ __align__(16) char uni[4][8192];
    __shared__ float redbuf[2][32][4];
    char* ubase = uni[w];

    s16x8 quh[2], qul[2], qvh[2], qvl[2];
#pragma unroll
    for (int i = 0; i < 2; ++i) {
        const float* qrow = q_ws + (bh * Tn + t0 + 16 * i + lr) * DHn + lg * 8;
        float4 qa = *(const float4*)qrow;
        float4 qb = *(const float4*)(qrow + 4);
        float qv8[8] = {qa.x, qa.y, qa.z, qa.w, qb.x, qb.y, qb.z, qb.w};
#pragma unroll
        for (int j = 0; j < 8; ++j) {
            const float uj = ub[h * DHn + lg * 8 + j];
            const float vj = vb[h * DHn + lg * 8 + j];
            float xu = qv8[j] + uj;
            unsigned short hu = f2bf(xu);
            quh[i][j] = (short)hu; qul[i][j] = (short)f2bf(xu - bf2f(hu));
            float xv = qv8[j] + vj;
            unsigned short hv = f2bf(xv);
            qvh[i][j] = (short)hv; qvl[i][j] = (short)f2bf(xv - bf2f(hv));
        }
    }
    float mv[8];
#pragma unroll
    for (int m = 0; m < 8; ++m)
        mv[m] = maskw[b * Tn + w * 128 + m * 16 + lr];

    auto posTile = [&](int i, int jt) -> f32x4 {
        int pidx = pbase + w * 128 + jt * 16 + lr;
        if (pidx > Pn - 1) pidx = Pn - 1;
        const size_t po = (bh * Pn + pidx) * DHn + lg * 8;
        s16x8 ph = *(const s16x8*)(p_hi + po);
        s16x8 pl = *(const s16x8*)(p_lo + po);
        f32x4 t = {0.f, 0.f, 0.f, 0.f};
        return mfma3(qvh[i], qvl[i], ph, pl, t);
    };

    f32x4 sc[2][8];
    f32x4 p0a = posTile(0, 1);
    f32x4 p1a = posTile(1, 0);
    const int ubb = lr - 4 * lg + 31;

#pragma unroll
    for (int m = 0; m < 8; ++m) {
        f32x4 p0b = posTile(0, m + 2);
        f32x4 p1b = posTile(1, m + 1);
        float bvls[2][4];
#pragma unroll
        for (int i2 = 0; i2 < 2; ++i2)
#pragma unroll
            for (int r2 = 0; r2 < 4; ++r2)
                bvls[i2][r2] = bf2f(biasw[((size_t)b * Tn + t0 + 16 * i2 + 4 * lg + r2) * Tn
                                          + w * 128 + m * 16 + lr]);
        const size_t ko = (bh * Tn + w * 128 + m * 16 + lr) * DHn + lg * 8;
        s16x8 kh = *(const s16x8*)(k_hi + ko);
        s16x8 kl = *(const s16x8*)(k_lo + ko);
#pragma unroll
        for (int i = 0; i < 2; ++i) {
            f32x4 c = {0.f, 0.f, 0.f, 0.f};
            c = mfma3(quh[i], qul[i], kh, kl, c);
            f32x4 Pa = (i == 0) ? p0a : p1a;
            f32x4 Pb = (i == 0) ? p0b : p1b;
            f32x4 out;
#pragma unroll
            for (int r2 = 0; r2 < 4; ++r2) {
                const int u = ubb - r2;
                const int src = (l & 48) | (u & 15);
                float pa = __shfl(Pa[r2], src, 64);
                float pb = __shfl(Pb[r2], src, 64);
                float pv = (u < 32) ? pa : pb;
                float v = (c[r2] + pv) * scale + bvls[i][r2];
                if (mv[m] != 0.0f) v = -10000.0f;
                out[r2] = v;
            }
            sc[i][m] = out;
        }
        p0a = p0b; p1a = p1b;
    }

    float rowm[2][4], inv[2][4];
#pragma unroll
    for (int i = 0; i < 2; ++i)
#pragma unroll
        for (int r2 = 0; r2 < 4; ++r2) {
            float mx = -1e30f;
#pragma unroll
            for (int m = 0; m < 8; ++m) mx = fmaxf(mx, sc[i][m][r2]);
#pragma unroll
            for (int off = 1; off < 16; off <<= 1) mx = fmaxf(mx, __shfl_xor(mx, off, 64));
            if (lr == 0) redbuf[0][16 * i + 4 * lg + r2][w] = mx;
        }
    __syncthreads();
#pragma unroll
    for (int i = 0; i < 2; ++i)
#pragma unroll
        for (int r2 = 0; r2 < 4; ++r2) {
            float4 mm = *(const float4*)redbuf[0][16 * i + 4 * lg + r2];
            rowm[i][r2] = fmaxf(fmaxf(mm.x, mm.y), fmaxf(mm.z, mm.w));
        }
    float psum[2][4] = {};
#pragma unroll
    for (int i = 0; i < 2; ++i)
#pragma unroll
        for (int m = 0; m < 8; ++m)
#pragma unroll
            for (int r2 = 0; r2 < 4; ++r2) {
                float e = __expf(sc[i][m][r2] - rowm[i][r2]);
                sc[i][m][r2] = e;
                psum[i][r2] += e;
            }
#pragma unroll
    for (int i = 0; i < 2; ++i)
#pragma unroll
        for (int r2 = 0; r2 < 4; ++r2) {
            float s = psum[i][r2];
#pragma unroll
            for (int off = 1; off < 16; off <<= 1) s += __shfl_xor(s, off, 64);
            if (lr == 0) redbuf[1][16 * i + 4 * lg + r2][w] = s;
        }
    __syncthreads();
#pragma unroll
    for (int i = 0; i < 2; ++i)
#pragma unroll
        for (int r2 = 0; r2 < 4; ++r2) {
            float4 ss = *(const float4*)redbuf[1][16 * i + 4 * lg + r2];
            inv[i][r2] = 1.0f / (ss.x + ss.y + ss.z + ss.w);
        }

    f32x4 cacc[2][2] = {};
#pragma unroll
    for (int sh = 0; sh < 2; ++sh) {
        __syncthreads();
#pragma unroll
        for (int mm2 = 0; mm2 < 4; ++mm2) {
            const int m = sh * 4 + mm2;
#pragma unroll
            for (int i = 0; i < 2; ++i)
#pragma unroll
                for (int r2 = 0; r2 < 4; ++r2) {
                    const int trow = 16 * i + 4 * lg + r2;
                    float a = sc[i][m][r2] * inv[i][r2];
                    unsigned short ah16 = f2bf(a);
                    unsigned short al16 = f2bf(a - bf2f(ah16));
                    const int cbyte = (mm2 * 16 + lr) * 2;
                    const int off = trow * 128 + (cbyte ^ ((trow & 7) << 4));
                    *(unsigned short*)(ubase + off) = ah16;
                    *(unsigned short*)(ubase + 4096 + off) = al16;
                }
        }
        __syncthreads();
#pragma unroll
        for (int ks = 0; ks < 2; ++ks) {
            s16x8 pah[2], pal[2];
#pragma unroll
            for (int i = 0; i < 2; ++i) {
                const int trow = 16 * i + lr;
                const int cbyte = ks * 64 + lg * 16;
                const int off = trow * 128 + (cbyte ^ ((trow & 7) << 4));
                pah[i] = *(const s16x8*)(ubase + off);
                pal[i] = *(const s16x8*)(ubase + 4096 + off);
            }
#pragma unroll
            for (int n = 0; n < 2; ++n) {
                const int sg = w * 128 + sh * 64 + ks * 32 + lg * 8;
                const size_t vo = (bh * DHn + n * 16 + lr) * Tn + sg;
                s16x8 vh = *(const s16x8*)(vt_hi + vo);
                s16x8 vl = *(const s16x8*)(vt_lo + vo);
#pragma unroll
                for (int i = 0; i < 2; ++i)
                    cacc[i][n] = mfma3(pah[i], pal[i], vh, vl, cacc[i][n]);
            }
        }
    }

    __syncthreads();  // all PV reads of attn bufs complete before ctxred overwrite
    {
        float* cr = (float*)ubase;
#pragma unroll
        for (int i = 0; i < 2; ++i)
#pragma unroll
            for (int n = 0; n < 2; ++n)
#pragma unroll
                for (int r2 = 0; r2 < 4; ++r2)
                    cr[(16 * i + 4 * lg + r2) * 36 + n * 16 + lr] = cacc[i][n][r2];
    }
    __syncthreads();
    {
        const int trow = tid >> 3, d0 = (tid & 7) * 4;
        float4 s0 = *(const float4*)((float*)uni[0] + trow * 36 + d0);
        float4 s1 = *(const float4*)((float*)uni[1] + trow * 36 + d0);
        float4 s2 = *(const float4*)((float*)uni[2] + trow * 36 + d0);
        float4 s3 = *(const float4*)((float*)uni[3] + trow * 36 + d0);
        float4 o = make_float4(s0.x + s1.x + s2.x + s3.x, s0.y + s1.y + s2.y + s3.y,
                               s0.z + s1.z + s2.z + s3.z, s0.w + s1.w + s2.w + s3.w);
        *(float4*)(ctx + ((size_t)b * Tn + t0 + trow) * Dn + h * DHn + d0) = o;
    }
}

// ---------------------------------------------------------------------------
extern "C" void kernel_launch(void* const* d_in, const int* in_sizes, int n_in,
                              void* d_out, int out_size, void* d_ws, size_t ws_size,
                              hipStream_t stream) {
    const float* query = (const float*)d_in[0];
    const float* key   = (const float*)d_in[1];
    const float* value = (const float*)d_in[2];
    const float* pos   = (const float*)d_in[3];
    const unsigned char* mask = (const unsigned char*)d_in[4];
    const float* bpp = (const float*)d_in[5];
    const float* Wq = (const float*)d_in[6];
    const float* bq = (const float*)d_in[7];
    const float* Wk = (const float*)d_in[8];
    const float* bk = (const float*)d_in[9];
    const float* Wv = (const float*)d_in[10];
    const float* bv = (const float*)d_in[11];
    const float* Wp = (const float*)d_in[12];
    const float* Wo = (const float*)d_in[13];
    const float* bo = (const float*)d_in[14];
    const float* ub = (const float*)d_in[15];
    const float* vbias = (const float*)d_in[16];
    const float* c1w = (const float*)d_in[17];
    const float* c1b = (const float*)d_in[18];
    const float* c2w = (const float*)d_in[19];
    const float* c2b = (const float*)d_in[20];

    const size_t qkvE = (size_t)Bn * Hn * Tn * DHn;   // 4.19M
    const size_t posE = (size_t)Bn * Hn * Pn * DHn;   // 8.38M

    char* wsb = (char*)d_ws;
    unsigned short* bias_ws = (unsigned short*)wsb;             // [B,T,T] bf16
    float* mask_ws = (float*)(wsb + sizeof(unsigned short) * (size_t)Bn * Tn * Tn);
    float* q_ws    = mask_ws + Bn * Tn;                          // [B,H,T,DH] f32
    float* ctx_ws  = q_ws + qkvE;                                // [B,T,D] f32
    unsigned short* k_hi = (unsigned short*)(ctx_ws + (size_t)Bn * Tn * Dn);
    unsigned short* k_lo = k_hi + qkvE;
    unsigned short* v_hi = k_lo + qkvE;                          // [B,H,DH,T]
    unsigned short* v_lo = v_hi + qkvE;
    unsigned short* p_hi = v_lo + qkvE;                          // [B,H,P,DH]
    unsigned short* p_lo = p_hi + posE;
    unsigned short* wall_hi = p_lo + posE;                       // 5 x [D,D]
    unsigned short* wall_lo = wall_hi + 5 * wE;

    // weight order: 0=Wq 1=Wk 2=Wv 3=Wp 4=Wo
    split_weights_kernel<<<dim3(64, 5), dim3(256), 0, stream>>>(
        Wq, Wk, Wv, Wp, Wo, wall_hi, wall_lo);
    mask_decode_kernel<<<dim3(1), dim3(256), 0, stream>>>(mask, mask_ws);
    conv_bias_kernel<<<dim3(8, 8, Bn), dim3(256), 0, stream>>>(
        bpp, c1w, c1b, c2w, c2b, bias_ws);

    gemm_qkvp_kernel<<<dim3(4, 128, 4), dim3(256), 0, stream>>>(
        query, key, value, pos, wall_hi, wall_lo, bq, bk, bv,
        q_ws, k_hi, k_lo, v_hi, v_lo, p_hi, p_lo);

    attn_mfma_kernel<<<dim3(4096), dim3(256), 0, stream>>>(
        q_ws, k_hi, k_lo, v_hi, v_lo, p_hi, p_lo, bias_ws, mask_ws, ub, vbias, ctx_ws);

    gemm_o_kernel<<<dim3(8, 64), dim3(256), 0, stream>>>(
        ctx_ws, wall_hi + 4 * wE, wall_lo + 4 * wE, bo, (float*)d_out);
}